// Round 1
// baseline (1321.374 us; speedup 1.0000x reference)
//
#include <hip/hip_runtime.h>
#include <cmath>
#include <cstdint>

// ============================================================================
// Compile-time replication of the BigBird block mask.
// Reproduces np.random.default_rng(0) → SeedSequence(0) → PCG64 (XSL-RR 128)
// → Generator.choice(32, size=2, replace=False) per row (Floyd's algorithm +
// Lemire bounded uint32 + the trailing _shuffle_int draw).
// ============================================================================
typedef unsigned int u32;
typedef unsigned long long u64;
typedef unsigned __int128 u128;

struct MaskBits { u32 row[32]; };

struct Pcg {
  u128 state; u128 inc;
  bool has32; u32 buf32;
};

constexpr u128 pcg_mul() {
  return (((u128)2549297995355413924ULL) << 64) | (u128)4865540595714422341ULL;
}

constexpr u64 pcg_next64(Pcg& s) {
  s.state = s.state * pcg_mul() + s.inc;
  u64 hi = (u64)(s.state >> 64);
  u64 lo = (u64)s.state;
  unsigned rot = (unsigned)(s.state >> 122) & 63u;
  u64 x = hi ^ lo;
  return (x >> rot) | (x << ((64u - rot) & 63u));
}

constexpr u32 pcg_next32(Pcg& s) {
  if (s.has32) { s.has32 = false; return s.buf32; }
  u64 n = pcg_next64(s);
  s.has32 = true; s.buf32 = (u32)(n >> 32);
  return (u32)n;
}

// numpy bounded_lemire_uint32: uniform on [0, rng] inclusive, rng < 0xffffffff
constexpr u32 lemire32(Pcg& s, u32 rng) {
  u32 rng_excl = rng + 1u;
  u64 m = (u64)pcg_next32(s) * (u64)rng_excl;
  u32 leftover = (u32)m;
  if (leftover < rng_excl) {
    u32 threshold = (0xFFFFFFFFu - rng) % rng_excl;
    while (leftover < threshold) {
      m = (u64)pcg_next32(s) * (u64)rng_excl;
      leftover = (u32)m;
    }
  }
  return (u32)(m >> 32);
}

constexpr Pcg pcg_seeded_from_zero() {
  // SeedSequence(0): entropy words = [0]; pool_size = 4.
  u32 pool[4] = {0, 0, 0, 0};
  u32 hc = 0x43b0d7e5u;                 // INIT_A
  for (int i = 0; i < 4; ++i) {         // all entropy words beyond [0] are 0
    u32 v = 0u;
    v ^= hc; hc = hc * 0x931e8875u;     // MULT_A
    v = v * hc; v ^= v >> 16;
    pool[i] = v;
  }
  for (int src = 0; src < 4; ++src) {
    for (int dst = 0; dst < 4; ++dst) {
      if (src == dst) continue;
      u32 v = pool[src];
      v ^= hc; hc = hc * 0x931e8875u;
      v = v * hc; v ^= v >> 16;
      u32 r = (pool[dst] * 0xca01f9ddu) ^ (v * 0x4973f715u); // MIX_MULT_L/R
      r ^= r >> 16;
      pool[dst] = r;
    }
  }
  // generate_state(4, uint64) -> 8 uint32 words, viewed little-endian as u64
  u32 st[8] = {};
  u32 hb = 0x8b51f9ddu;                 // INIT_B
  for (int i = 0; i < 8; ++i) {
    u32 v = pool[i & 3];
    v ^= hb; hb = hb * 0x58f38dedu;     // MULT_B
    v = v * hb; v ^= v >> 16;
    st[i] = v;
  }
  u64 w0 = (u64)st[0] | ((u64)st[1] << 32);
  u64 w1 = (u64)st[2] | ((u64)st[3] << 32);
  u64 w2 = (u64)st[4] | ((u64)st[5] << 32);
  u64 w3 = (u64)st[6] | ((u64)st[7] << 32);
  u128 initstate = (((u128)w0) << 64) | (u128)w1;  // PCG_128BIT_CONSTANT(v[0], v[1])
  u128 initseq   = (((u128)w2) << 64) | (u128)w3;  // PCG_128BIT_CONSTANT(v[2], v[3])
  Pcg s{};
  s.state = 0; s.inc = (initseq << 1) | (u128)1; s.has32 = false; s.buf32 = 0;
  s.state = s.state * pcg_mul() + s.inc;
  s.state += initstate;
  s.state = s.state * pcg_mul() + s.inc;
  return s;
}

constexpr MaskBits make_mask() {
  bool m[32][32] = {};
  for (int i = 0; i < 32; ++i)
    for (int j = 0; j < 32; ++j) {
      int d = i - j; if (d < 0) d = -d;
      m[i][j] = (d <= 1);                       // window NW=3
    }
  for (int j = 0; j < 32; ++j) m[0][j] = true;  // global rows (NG=1)
  for (int i = 0; i < 32; ++i) m[i][0] = true;  // global cols
  Pcg s = pcg_seeded_from_zero();
  for (int r = 0; r < 32; ++r) {
    // Generator.choice(32, size=2, replace=False): Floyd's, hash set of 4
    u64 hs[4] = {~0ull, ~0ull, ~0ull, ~0ull};
    u64 idx[2] = {0, 0};
    for (int j = 30; j <= 31; ++j) {
      u64 val = (u64)lemire32(s, (u32)j);
      u64 loc = val & 3u;
      while (hs[loc] != ~0ull && hs[loc] != val) loc = (loc + 1) & 3u;
      if (hs[loc] == ~0ull) { hs[loc] = val; idx[j - 30] = val; }
      else {
        loc = (u64)j & 3u;
        while (hs[loc] != ~0ull) loc = (loc + 1) & 3u;
        hs[loc] = (u64)j; idx[j - 30] = (u64)j;
      }
    }
    u32 jj = lemire32(s, 1u);   // _shuffle_int(2, 1, idx): i=1 swap
    u64 t = idx[1]; idx[1] = idx[jj]; idx[jj] = t;
    m[r][(int)idx[0]] = true;
    m[r][(int)idx[1]] = true;
  }
  MaskBits mb{};
  for (int i = 0; i < 32; ++i) {
    u32 bits = 0;
    for (int j = 0; j < 32; ++j) if (m[i][j]) bits |= (1u << j);
    mb.row[i] = bits;
  }
  return mb;
}

static constexpr MaskBits kMask = make_mask();

// ============================================================================
// Generic fp32 GEMM: C[M,N] = A[M,K] · W[N,K]^T + bias[N]  (optional ReLU)
// 256 threads; per-thread (BM/64)x(BN/64) quadrants of 4x4; BK=16.
// LDS leading dims padded +4 -> all ds accesses <=2-way bank aliasing (free).
// ============================================================================
template<int BM, int BN, bool RELU>
__global__ __launch_bounds__(256) void gemm_bt(const float* __restrict__ A,
                                               const float* __restrict__ W,
                                               const float* __restrict__ bias,
                                               float* __restrict__ C,
                                               int M, int N, int K) {
  constexpr int BK = 16;
  constexpr int MP = BM / 64, NP = BN / 64;
  constexpr int LDA = BM + 4, LDB = BN + 4;
  __shared__ float As[BK][LDA];   // transposed: As[k][m]
  __shared__ float Bs[BK][LDB];   // transposed: Bs[k][n]

  const int tid = threadIdx.x;
  const int tx = tid & 15;        // N within 64-quadrant
  const int ty = tid >> 4;        // M within 64-quadrant
  const int bm = blockIdx.y * BM;
  const int bn = blockIdx.x * BN;
  const int sr = tid >> 2;        // staging row 0..63
  const int sk = (tid & 3) * 4;   // staging k   0,4,8,12

  float acc[MP][NP][4][4] = {};

  const float* Ap = A + (size_t)(bm + sr) * K + sk;
  const float* Wp = W + (size_t)(bn + sr) * K + sk;

  for (int k0 = 0; k0 < K; k0 += BK) {
    float4 av[MP], bv[NP];
#pragma unroll
    for (int p = 0; p < MP; ++p)
      av[p] = *(const float4*)(Ap + (size_t)(p * 64) * K + k0);
#pragma unroll
    for (int p = 0; p < NP; ++p)
      bv[p] = *(const float4*)(Wp + (size_t)(p * 64) * K + k0);
    __syncthreads();   // previous iteration's LDS reads complete
#pragma unroll
    for (int p = 0; p < MP; ++p) {
      As[sk + 0][p * 64 + sr] = av[p].x;
      As[sk + 1][p * 64 + sr] = av[p].y;
      As[sk + 2][p * 64 + sr] = av[p].z;
      As[sk + 3][p * 64 + sr] = av[p].w;
    }
#pragma unroll
    for (int p = 0; p < NP; ++p) {
      Bs[sk + 0][p * 64 + sr] = bv[p].x;
      Bs[sk + 1][p * 64 + sr] = bv[p].y;
      Bs[sk + 2][p * 64 + sr] = bv[p].z;
      Bs[sk + 3][p * 64 + sr] = bv[p].w;
    }
    __syncthreads();
#pragma unroll
    for (int k = 0; k < BK; ++k) {
      float a_[MP][4], b_[NP][4];
#pragma unroll
      for (int p = 0; p < MP; ++p) {
        float4 v = *(const float4*)&As[k][p * 64 + ty * 4];
        a_[p][0] = v.x; a_[p][1] = v.y; a_[p][2] = v.z; a_[p][3] = v.w;
      }
#pragma unroll
      for (int p = 0; p < NP; ++p) {
        float4 v = *(const float4*)&Bs[k][p * 64 + tx * 4];
        b_[p][0] = v.x; b_[p][1] = v.y; b_[p][2] = v.z; b_[p][3] = v.w;
      }
#pragma unroll
      for (int mp = 0; mp < MP; ++mp)
#pragma unroll
        for (int i = 0; i < 4; ++i)
#pragma unroll
          for (int np2 = 0; np2 < NP; ++np2)
#pragma unroll
            for (int j = 0; j < 4; ++j)
              acc[mp][np2][i][j] = fmaf(a_[mp][i], b_[np2][j], acc[mp][np2][i][j]);
    }
  }

#pragma unroll
  for (int mp = 0; mp < MP; ++mp)
#pragma unroll
    for (int i = 0; i < 4; ++i) {
      size_t row = (size_t)(bm + mp * 64 + ty * 4 + i);
#pragma unroll
      for (int np2 = 0; np2 < NP; ++np2) {
        int col = bn + np2 * 64 + tx * 4;
        float4 bb = *(const float4*)(bias + col);
        float4 ov;
        ov.x = acc[mp][np2][i][0] + bb.x;
        ov.y = acc[mp][np2][i][1] + bb.y;
        ov.z = acc[mp][np2][i][2] + bb.z;
        ov.w = acc[mp][np2][i][3] + bb.w;
        if (RELU) {
          ov.x = fmaxf(ov.x, 0.f); ov.y = fmaxf(ov.y, 0.f);
          ov.z = fmaxf(ov.z, 0.f); ov.w = fmaxf(ov.w, 0.f);
        }
        *(float4*)(C + row * (size_t)N + col) = ov;
      }
    }
}

// ============================================================================
// Block-sparse flash attention. One block per (qblock, head, batch).
// qkv: [B, S, 3*512]; q at +0, k at +512, v at +1024 (head offset h*64).
// Q,K staged transposed ([d][row]) for conflict-free outer-product reads.
// Softmax (wave0) runs concurrently with V staging (waves 1-3).
// ============================================================================
__global__ __launch_bounds__(256) void attn_sparse(const float* __restrict__ qkv,
                                                   float* __restrict__ ctx,
                                                   MaskBits mask) {
  constexpr int PAD = 68;
  __shared__ float Qt[64][PAD];     // [d][r], pre-scaled by 1/8
  __shared__ float KV[64][PAD];     // K phase: [d][c]; V phase: [c][d]
  __shared__ float Ss[64][65];      // scores → probabilities
  __shared__ float mrow[64], lrow[64], arow[64];

  const int qb = blockIdx.x, h = blockIdx.y, b = blockIdx.z;
  const int tid = threadIdx.x;
  const int tx = tid & 15, ty = tid >> 4;
  const size_t RS = 1536;
  const float* qbase = qkv + ((size_t)b * 2048 + (size_t)qb * 64) * RS + h * 64;
  const float* kbase = qkv + (size_t)b * 2048 * RS + 512 + h * 64;
  const float* vbase = kbase + 512;

  { // stage Q transposed & scaled
    int r = tid >> 2;
    int c0 = (tid & 3) * 16;
    const float* src = qbase + (size_t)r * RS + c0;
#pragma unroll
    for (int u = 0; u < 4; ++u) {
      float4 v = *(const float4*)(src + 4 * u);
      Qt[c0 + 4 * u + 0][r] = v.x * 0.125f;
      Qt[c0 + 4 * u + 1][r] = v.y * 0.125f;
      Qt[c0 + 4 * u + 2][r] = v.z * 0.125f;
      Qt[c0 + 4 * u + 3][r] = v.w * 0.125f;
    }
  }
  if (tid < 64) { mrow[tid] = -INFINITY; lrow[tid] = 0.f; }
  float o[4][4] = {};
  __syncthreads();

  const u32 bits = mask.row[qb];
  for (int kb = 0; kb < 32; ++kb) {
    if (!((bits >> kb) & 1u)) continue;
    __syncthreads();               // prior PV reads of KV/Ss complete
    { // stage K transposed
      int r = tid >> 2;
      int c0 = (tid & 3) * 16;
      const float* src = kbase + (size_t)(kb * 64 + r) * RS + c0;
#pragma unroll
      for (int u = 0; u < 4; ++u) {
        float4 v = *(const float4*)(src + 4 * u);
        KV[c0 + 4 * u + 0][r] = v.x;
        KV[c0 + 4 * u + 1][r] = v.y;
        KV[c0 + 4 * u + 2][r] = v.z;
        KV[c0 + 4 * u + 3][r] = v.w;
      }
    }
    __syncthreads();
    // S = (Q/8) · K^T   (4x4 per thread, outer product over d)
    float sacc[4][4] = {};
#pragma unroll 8
    for (int d = 0; d < 64; ++d) {
      float4 qa = *(const float4*)&Qt[d][ty * 4];
      float4 kb4 = *(const float4*)&KV[d][tx * 4];
      float a_[4] = {qa.x, qa.y, qa.z, qa.w};
      float b_[4] = {kb4.x, kb4.y, kb4.z, kb4.w};
#pragma unroll
      for (int i = 0; i < 4; ++i)
#pragma unroll
        for (int j = 0; j < 4; ++j)
          sacc[i][j] = fmaf(a_[i], b_[j], sacc[i][j]);
    }
#pragma unroll
    for (int i = 0; i < 4; ++i)
#pragma unroll
      for (int j = 0; j < 4; ++j)
        Ss[ty * 4 + i][tx * 4 + j] = sacc[i][j];
    __syncthreads();
    // wave0: online-softmax row update | waves 1-3: stage V (row-major)
    if (tid < 64) {
      const int r = tid;
      float mold = mrow[r];
      float mx = mold;
      for (int c = 0; c < 64; ++c) mx = fmaxf(mx, Ss[r][c]);
      float al = expf(mold - mx);        // 0 on first visited block
      float sum = 0.f;
      for (int c = 0; c < 64; ++c) {
        float p = expf(Ss[r][c] - mx);
        Ss[r][c] = p;
        sum += p;
      }
      mrow[r] = mx;
      lrow[r] = lrow[r] * al + sum;
      arow[r] = al;
    } else {
      int idx = tid - 64;
      for (int w = idx; w < 1024; w += 192) {
        int r = w >> 4;
        int c0 = (w & 15) * 4;
        float4 v = *(const float4*)(vbase + (size_t)(kb * 64 + r) * RS + c0);
        *(float4*)&KV[r][c0] = v;        // V as [c][d]
      }
    }
    __syncthreads();
    // O = O*alpha + P·V
    float al[4];
#pragma unroll
    for (int i = 0; i < 4; ++i) al[i] = arow[ty * 4 + i];
#pragma unroll
    for (int i = 0; i < 4; ++i)
#pragma unroll
      for (int j = 0; j < 4; ++j) o[i][j] *= al[i];
#pragma unroll 8
    for (int c = 0; c < 64; ++c) {
      float4 vv = *(const float4*)&KV[c][tx * 4];
      float v_[4] = {vv.x, vv.y, vv.z, vv.w};
      float p_[4];
#pragma unroll
      for (int i = 0; i < 4; ++i) p_[i] = Ss[ty * 4 + i][c];
#pragma unroll
      for (int i = 0; i < 4; ++i)
#pragma unroll
        for (int j = 0; j < 4; ++j)
          o[i][j] = fmaf(p_[i], v_[j], o[i][j]);
    }
  }

  // epilogue: divide by l, scatter to ctx[b][s][h*64+d]
  float* dst = ctx + ((size_t)b * 2048 + (size_t)qb * 64) * 512 + h * 64;
#pragma unroll
  for (int i = 0; i < 4; ++i) {
    int r = ty * 4 + i;
    float inv = 1.f / lrow[r];
    float4 ov = {o[i][0] * inv, o[i][1] * inv, o[i][2] * inv, o[i][3] * inv};
    *(float4*)(dst + (size_t)r * 512 + tx * 4) = ov;
  }
}

// ============================================================================
// Fused residual add + LayerNorm over D=512. One block (256 thr) per row.
// ============================================================================
__global__ __launch_bounds__(256) void add_ln(const float* __restrict__ a,
                                              const float* __restrict__ bsrc,
                                              const float* __restrict__ g,
                                              const float* __restrict__ beta,
                                              float* __restrict__ out) {
  const int row = blockIdx.x;
  const int tid = threadIdx.x;
  const float2* a2 = (const float2*)(a + (size_t)row * 512);
  const float2* b2 = (const float2*)(bsrc + (size_t)row * 512);
  float2 va = a2[tid], vb = b2[tid];
  float x0 = va.x + vb.x, x1 = va.y + vb.y;
  float s = x0 + x1;
  float q = x0 * x0 + x1 * x1;
#pragma unroll
  for (int off = 32; off >= 1; off >>= 1) {
    s += __shfl_xor(s, off, 64);
    q += __shfl_xor(q, off, 64);
  }
  __shared__ float ws[4], wq[4];
  int wid = tid >> 6, lane = tid & 63;
  if (lane == 0) { ws[wid] = s; wq[wid] = q; }
  __syncthreads();
  float ts = ws[0] + ws[1] + ws[2] + ws[3];
  float tq = wq[0] + wq[1] + wq[2] + wq[3];
  float mu = ts * (1.0f / 512.0f);
  float var = tq * (1.0f / 512.0f) - mu * mu;
  float rstd = rsqrtf(var + 1e-5f);
  const float2* g2 = (const float2*)g;
  const float2* be2 = (const float2*)beta;
  float2 vg = g2[tid], vbt = be2[tid];
  float2 r;
  r.x = (x0 - mu) * rstd * vg.x + vbt.x;
  r.y = (x1 - mu) * rstd * vg.y + vbt.y;
  *(float2*)(out + (size_t)row * 512 + tid * 2) = r;
}

// ============================================================================
// Launch
// ============================================================================
extern "C" void kernel_launch(void* const* d_in, const int* in_sizes, int n_in,
                              void* d_out, int out_size, void* d_ws, size_t ws_size,
                              hipStream_t stream) {
  const float* x     = (const float*)d_in[0];
  const float* w_in  = (const float*)d_in[1];
  const float* b_in  = (const float*)d_in[2];
  const float* w_out = (const float*)d_in[3];
  const float* b_out = (const float*)d_in[4];
  const float* w1    = (const float*)d_in[5];
  const float* b1    = (const float*)d_in[6];
  const float* w2    = (const float*)d_in[7];
  const float* b2    = (const float*)d_in[8];
  const float* g1    = (const float*)d_in[9];
  const float* be1   = (const float*)d_in[10];
  const float* g2    = (const float*)d_in[11];
  const float* be2   = (const float*)d_in[12];
  float* out = (float*)d_out;

  float* ws  = (float*)d_ws;
  float* qkv = ws;                               // 8192*1536
  float* ctx = qkv + (size_t)8192 * 1536;        // 8192*512
  float* sa  = ctx + (size_t)8192 * 512;         // 8192*512
  float* x1  = sa  + (size_t)8192 * 512;         // 8192*512
  float* mid = x1  + (size_t)8192 * 512;         // 8192*2048
  float* ff  = mid + (size_t)8192 * 2048;        // 8192*512

  dim3 blk(256);

  // 1. qkv = x @ in_proj_w^T + in_proj_b          [8192,1536]
  gemm_bt<128, 128, false><<<dim3(1536 / 128, 8192 / 128), blk, 0, stream>>>(
      x, w_in, b_in, qkv, 8192, 1536, 512);
  // 2. block-sparse flash attention → ctx         [8192,512]
  attn_sparse<<<dim3(32, 8, 4), blk, 0, stream>>>(qkv, ctx, kMask);
  // 3. sa = ctx @ out_proj_w^T + out_proj_b       [8192,512]
  gemm_bt<128, 64, false><<<dim3(512 / 64, 8192 / 128), blk, 0, stream>>>(
      ctx, w_out, b_out, sa, 8192, 512, 512);
  // 4. x1 = LN(x + sa)
  add_ln<<<dim3(8192), blk, 0, stream>>>(x, sa, g1, be1, x1);
  // 5. mid = relu(x1 @ w1^T + b1)                 [8192,2048]
  gemm_bt<128, 128, true><<<dim3(2048 / 128, 8192 / 128), blk, 0, stream>>>(
      x1, w1, b1, mid, 8192, 2048, 512);
  // 6. ff = mid @ w2^T + b2                       [8192,512]
  gemm_bt<128, 64, false><<<dim3(512 / 64, 8192 / 128), blk, 0, stream>>>(
      mid, w2, b2, ff, 8192, 512, 2048);
  // 7. out = LN(x1 + ff)
  add_ln<<<dim3(8192), blk, 0, stream>>>(x1, ff, g2, be2, out);
}

// Round 3
// 1169.442 us; speedup vs baseline: 1.1299x; 1.1299x over previous
//
#include <hip/hip_runtime.h>
#include <cmath>
#include <cstdint>

// ============================================================================
// Compile-time replication of the BigBird block mask (np.random.default_rng(0)
// → SeedSequence(0) → PCG64 XSL-RR 128 → choice(32,2,replace=False) per row).
// ============================================================================
typedef unsigned int u32;
typedef unsigned long long u64;
typedef unsigned __int128 u128;

struct MaskBits { u32 row[32]; };

struct Pcg {
  u128 state; u128 inc;
  bool has32; u32 buf32;
};

constexpr u128 pcg_mul() {
  return (((u128)2549297995355413924ULL) << 64) | (u128)4865540595714422341ULL;
}

constexpr u64 pcg_next64(Pcg& s) {
  s.state = s.state * pcg_mul() + s.inc;
  u64 hi = (u64)(s.state >> 64);
  u64 lo = (u64)s.state;
  unsigned rot = (unsigned)(s.state >> 122) & 63u;
  u64 x = hi ^ lo;
  return (x >> rot) | (x << ((64u - rot) & 63u));
}

constexpr u32 pcg_next32(Pcg& s) {
  if (s.has32) { s.has32 = false; return s.buf32; }
  u64 n = pcg_next64(s);
  s.has32 = true; s.buf32 = (u32)(n >> 32);
  return (u32)n;
}

constexpr u32 lemire32(Pcg& s, u32 rng) {
  u32 rng_excl = rng + 1u;
  u64 m = (u64)pcg_next32(s) * (u64)rng_excl;
  u32 leftover = (u32)m;
  if (leftover < rng_excl) {
    u32 threshold = (0xFFFFFFFFu - rng) % rng_excl;
    while (leftover < threshold) {
      m = (u64)pcg_next32(s) * (u64)rng_excl;
      leftover = (u32)m;
    }
  }
  return (u32)(m >> 32);
}

constexpr Pcg pcg_seeded_from_zero() {
  u32 pool[4] = {0, 0, 0, 0};
  u32 hc = 0x43b0d7e5u;                 // INIT_A
  for (int i = 0; i < 4; ++i) {
    u32 v = 0u;
    v ^= hc; hc = hc * 0x931e8875u;     // MULT_A
    v = v * hc; v ^= v >> 16;
    pool[i] = v;
  }
  for (int src = 0; src < 4; ++src) {
    for (int dst = 0; dst < 4; ++dst) {
      if (src == dst) continue;
      u32 v = pool[src];
      v ^= hc; hc = hc * 0x931e8875u;
      v = v * hc; v ^= v >> 16;
      u32 r = (pool[dst] * 0xca01f9ddu) ^ (v * 0x4973f715u);
      r ^= r >> 16;
      pool[dst] = r;
    }
  }
  u32 st[8] = {};
  u32 hb = 0x8b51f9ddu;                 // INIT_B
  for (int i = 0; i < 8; ++i) {
    u32 v = pool[i & 3];
    v ^= hb; hb = hb * 0x58f38dedu;     // MULT_B
    v = v * hb; v ^= v >> 16;
    st[i] = v;
  }
  u64 w0 = (u64)st[0] | ((u64)st[1] << 32);
  u64 w1 = (u64)st[2] | ((u64)st[3] << 32);
  u64 w2 = (u64)st[4] | ((u64)st[5] << 32);
  u64 w3 = (u64)st[6] | ((u64)st[7] << 32);
  u128 initstate = (((u128)w0) << 64) | (u128)w1;
  u128 initseq   = (((u128)w2) << 64) | (u128)w3;
  Pcg s{};
  s.state = 0; s.inc = (initseq << 1) | (u128)1; s.has32 = false; s.buf32 = 0;
  s.state = s.state * pcg_mul() + s.inc;
  s.state += initstate;
  s.state = s.state * pcg_mul() + s.inc;
  return s;
}

constexpr MaskBits make_mask() {
  bool m[32][32] = {};
  for (int i = 0; i < 32; ++i)
    for (int j = 0; j < 32; ++j) {
      int d = i - j; if (d < 0) d = -d;
      m[i][j] = (d <= 1);
    }
  for (int j = 0; j < 32; ++j) m[0][j] = true;
  for (int i = 0; i < 32; ++i) m[i][0] = true;
  Pcg s = pcg_seeded_from_zero();
  for (int r = 0; r < 32; ++r) {
    u64 hs[4] = {~0ull, ~0ull, ~0ull, ~0ull};
    u64 idx[2] = {0, 0};
    for (int j = 30; j <= 31; ++j) {
      u64 val = (u64)lemire32(s, (u32)j);
      u64 loc = val & 3u;
      while (hs[loc] != ~0ull && hs[loc] != val) loc = (loc + 1) & 3u;
      if (hs[loc] == ~0ull) { hs[loc] = val; idx[j - 30] = val; }
      else {
        loc = (u64)j & 3u;
        while (hs[loc] != ~0ull) loc = (loc + 1) & 3u;
        hs[loc] = (u64)j; idx[j - 30] = (u64)j;
      }
    }
    u32 jj = lemire32(s, 1u);
    u64 t = idx[1]; idx[1] = idx[jj]; idx[jj] = t;
    m[r][(int)idx[0]] = true;
    m[r][(int)idx[1]] = true;
  }
  MaskBits mb{};
  for (int i = 0; i < 32; ++i) {
    u32 bits = 0;
    for (int j = 0; j < 32; ++j) if (m[i][j]) bits |= (1u << j);
    mb.row[i] = bits;
  }
  return mb;
}

static constexpr MaskBits kMask = make_mask();

// ============================================================================
// bf16 helpers (RTNE), header-free
// ============================================================================
typedef unsigned short ushortT;
typedef __attribute__((ext_vector_type(8))) short short8;     // MFMA A/B frag
typedef __attribute__((ext_vector_type(8))) unsigned short ushort8;
typedef __attribute__((ext_vector_type(4))) float f32x4;      // MFMA C/D frag

__device__ __forceinline__ ushortT f2bf(float x) {
  u32 u = __float_as_uint(x);
  return (ushortT)((u + 0x7fffu + ((u >> 16) & 1u)) >> 16);
}
__device__ __forceinline__ float bf2f(ushortT h) {
  return __uint_as_float(((u32)h) << 16);
}

// ============================================================================
// Elementwise fp32 -> (hi,lo) bf16 split. Grid-stride over float4 quads.
// ============================================================================
__global__ __launch_bounds__(256) void split_bf16(const float* __restrict__ src,
                                                  ushortT* __restrict__ hi,
                                                  ushortT* __restrict__ lo,
                                                  int n4) {
  for (int i = blockIdx.x * 256 + threadIdx.x; i < n4; i += gridDim.x * 256) {
    float4 v = ((const float4*)src)[i];
    ushort4 h, l;
    h.x = f2bf(v.x); l.x = f2bf(v.x - bf2f(h.x));
    h.y = f2bf(v.y); l.y = f2bf(v.y - bf2f(h.y));
    h.z = f2bf(v.z); l.z = f2bf(v.z - bf2f(h.z));
    h.w = f2bf(v.w); l.w = f2bf(v.w - bf2f(h.w));
    ((ushort4*)hi)[i] = h;
    ((ushort4*)lo)[i] = l;
  }
}

// ============================================================================
// Split-bf16 MFMA GEMM:  C[M,N] = A[M,K]·W[N,K]^T + bias  (3-term Markidis)
// A,W pre-split into hi/lo bf16. 128x128 tile, BK=32, 4 waves (2x2 of 64x64).
// LDS: 4 tiles [128 rows][32 k] bf16, 16B k-group slots XOR-swizzled by
// (row>>1)&3 -> <=2-way banking on ds_write_b128 and fragment ds_read_b128.
// EPI: 0 = fp32 C (+bias, opt ReLU); 1 = split hi/lo bf16 C (+bias, opt ReLU).
// ============================================================================
template<int EPI, bool RELU>
__global__ __launch_bounds__(256) void gemm_split(
    const ushortT* __restrict__ Ahi, const ushortT* __restrict__ Alo,
    const ushortT* __restrict__ Bhi, const ushortT* __restrict__ Blo,
    const float* __restrict__ bias,
    float* __restrict__ C, ushortT* __restrict__ Chi, ushortT* __restrict__ Clo,
    int N, int K) {
  __shared__ ushortT lds[4][128 * 32];

  const int tid = threadIdx.x;
  const int l = tid & 63;
  const int wid = tid >> 6;
  const int wr = wid >> 1, wc = wid & 1;          // 2x2 wave grid
  const int bm = blockIdx.y * 128, bn = blockIdx.x * 128;

  const int srow = tid >> 1;                      // staging row 0..127
  const int sh = tid & 1;                         // staging half (16 el)

  f32x4 acc[4][4] = {};

  const ushortT* srcs[4];
  srcs[0] = Ahi + (size_t)bm * K;
  srcs[1] = Alo + (size_t)bm * K;
  srcs[2] = Bhi + (size_t)bn * K;
  srcs[3] = Blo + (size_t)bn * K;

  const int swz = (srow >> 1) & 3;                // staging swizzle key

  for (int kc = 0; kc < K; kc += 32) {
    // ---- global loads to regs (2 x 16B per tile per thread) ----
    ushort8 stg[4][2];
#pragma unroll
    for (int t = 0; t < 4; ++t) {
      const ushortT* p = srcs[t] + (size_t)srow * K + kc + sh * 16;
      stg[t][0] = *(const ushort8*)p;
      stg[t][1] = *(const ushort8*)(p + 8);
    }
    __syncthreads();     // previous chunk's fragment reads complete
#pragma unroll
    for (int t = 0; t < 4; ++t) {
#pragma unroll
      for (int g2 = 0; g2 < 2; ++g2) {
        int g = 2 * sh + g2;
        int slot = g ^ swz;
        *(ushort8*)&lds[t][srow * 32 + slot * 8] = stg[t][g2];
      }
    }
    __syncthreads();

    // ---- fragment reads + 48 MFMA ----
    short8 ah[4], al_[4], bh[4], bl[4];
    const int g = l >> 4;
    const int rl = l & 15;
#pragma unroll
    for (int m = 0; m < 4; ++m) {
      int ra = wr * 64 + m * 16 + rl;
      int idx = ra * 32 + (g ^ ((ra >> 1) & 3)) * 8;
      ah[m]  = *(const short8*)&lds[0][idx];
      al_[m] = *(const short8*)&lds[1][idx];
    }
#pragma unroll
    for (int n = 0; n < 4; ++n) {
      int rb = wc * 64 + n * 16 + rl;
      int idx = rb * 32 + (g ^ ((rb >> 1) & 3)) * 8;
      bh[n] = *(const short8*)&lds[2][idx];
      bl[n] = *(const short8*)&lds[3][idx];
    }
#pragma unroll
    for (int m = 0; m < 4; ++m)
#pragma unroll
      for (int n = 0; n < 4; ++n) {
        acc[m][n] = __builtin_amdgcn_mfma_f32_16x16x32_bf16(ah[m],  bh[n], acc[m][n], 0, 0, 0);
        acc[m][n] = __builtin_amdgcn_mfma_f32_16x16x32_bf16(al_[m], bh[n], acc[m][n], 0, 0, 0);
        acc[m][n] = __builtin_amdgcn_mfma_f32_16x16x32_bf16(ah[m],  bl[n], acc[m][n], 0, 0, 0);
      }
  }

  // ---- epilogue: C/D layout col = lane&15, row = (lane>>4)*4 + reg ----
  const int cg = l & 15, rg = (l >> 4) * 2;   // note: rows (l>>4)*4 + r
#pragma unroll
  for (int m = 0; m < 4; ++m)
#pragma unroll
    for (int n = 0; n < 4; ++n) {
      int col = bn + wc * 64 + n * 16 + cg;
      float bb = bias[col];
#pragma unroll
      for (int r = 0; r < 4; ++r) {
        int row = bm + wr * 64 + m * 16 + (l >> 4) * 4 + r;
        float v = acc[m][n][r] + bb;
        if (RELU) v = fmaxf(v, 0.f);
        size_t o = (size_t)row * N + col;
        if (EPI == 0) {
          C[o] = v;
        } else {
          ushortT h = f2bf(v);
          Chi[o] = h;
          Clo[o] = f2bf(v - bf2f(h));
        }
      }
    }
  (void)rg;
}

// ============================================================================
// Block-sparse flash attention, v3 (shared K/V tile -> 49.9 KB LDS).
// One block (256 thr) per (qblock, head, batch). Register softmax via
// 16-lane shfl_xor row groups. P stored transposed in wave-private columns.
// K_next and V_cur prefetched in registers. Writes ctx as split hi/lo bf16.
// ============================================================================
__global__ __launch_bounds__(256) void attn_sparse(const float* __restrict__ qkv,
                                                   ushortT* __restrict__ ctx_hi,
                                                   ushortT* __restrict__ ctx_lo,
                                                   MaskBits mask) {
  constexpr int LD = 65;
  __shared__ float Qs[64][LD];    // [row][d], pre-scaled by 1/8
  __shared__ float KVs[64][LD];   // K phase: [key][d]; then V: [key][d]
  __shared__ float Ps[64][LD];    // transposed: [key][row]

  const int qb = blockIdx.x, h = blockIdx.y, b = blockIdx.z;
  const int tid = threadIdx.x;
  const int tx = tid & 15, ty = tid >> 4;
  const size_t RS = 1536;
  const float* qbase = qkv + ((size_t)b * 2048 + (size_t)qb * 64) * RS + h * 64;
  const float* kbase = qkv + (size_t)b * 2048 * RS + 512 + h * 64;
  const float* vbase = kbase + 512;

  const int sr = tid >> 2;            // staging row 0..63
  const int sc = (tid & 3) * 16;      // staging col 0,16,32,48

  { // stage Q (scaled)
    const float* src = qbase + (size_t)sr * RS + sc;
#pragma unroll
    for (int u = 0; u < 4; ++u) {
      float4 v = *(const float4*)(src + 4 * u);
      v.x *= 0.125f; v.y *= 0.125f; v.z *= 0.125f; v.w *= 0.125f;
      *(float4*)&Qs[sr][sc + 4 * u] = v;
    }
  }

  const u32 bits = mask.row[qb];
  int kb = (int)__builtin_ctz(bits);
  float4 cv[4];                       // V of current block (regs)
  { // stage K0 to LDS, V0 to regs
    const float* ks = kbase + (size_t)(kb * 64 + sr) * RS + sc;
    const float* vs = vbase + (size_t)(kb * 64 + sr) * RS + sc;
#pragma unroll
    for (int u = 0; u < 4; ++u) {
      *(float4*)&KVs[sr][sc + 4 * u] = *(const float4*)(ks + 4 * u);
      cv[u] = *(const float4*)(vs + 4 * u);
    }
  }

  float m_[4] = {-INFINITY, -INFINITY, -INFINITY, -INFINITY};
  float l_[4] = {0.f, 0.f, 0.f, 0.f};
  float o[4][4] = {};
  u32 rem = bits & (bits - 1u);
  __syncthreads();

  for (;;) {
    // ---- prefetch next K/V into regs ----
    float4 nk[4], nv[4];
    int nkb = -1;
    if (rem) {
      nkb = (int)__builtin_ctz(rem);
      rem &= rem - 1u;
      const float* ks = kbase + (size_t)(nkb * 64 + sr) * RS + sc;
      const float* vs = vbase + (size_t)(nkb * 64 + sr) * RS + sc;
#pragma unroll
      for (int u = 0; u < 4; ++u) {
        nk[u] = *(const float4*)(ks + 4 * u);
        nv[u] = *(const float4*)(vs + 4 * u);
      }
    }

    // ---- S = (Q/8)·K^T ----
    float s[4][4] = {};
#pragma unroll 4
    for (int d0 = 0; d0 < 64; d0 += 4) {
      float4 qa[4], kv[4];
#pragma unroll
      for (int i = 0; i < 4; ++i) qa[i] = *(const float4*)&Qs[4 * ty + i][d0];
#pragma unroll
      for (int j = 0; j < 4; ++j) kv[j] = *(const float4*)&KVs[4 * tx + j][d0];
#pragma unroll
      for (int i = 0; i < 4; ++i)
#pragma unroll
        for (int j = 0; j < 4; ++j) {
          s[i][j] = fmaf(qa[i].x, kv[j].x, s[i][j]);
          s[i][j] = fmaf(qa[i].y, kv[j].y, s[i][j]);
          s[i][j] = fmaf(qa[i].z, kv[j].z, s[i][j]);
          s[i][j] = fmaf(qa[i].w, kv[j].w, s[i][j]);
        }
    }
    __syncthreads();                 // QK^T reads of KVs done

    // ---- write V_cur into KVs (overlaps with register softmax) ----
#pragma unroll
    for (int u = 0; u < 4; ++u) *(float4*)&KVs[sr][sc + 4 * u] = cv[u];

    // ---- register online softmax (16-lane row groups) ----
    float al[4];
#pragma unroll
    for (int i = 0; i < 4; ++i) {
      float mx = fmaxf(fmaxf(s[i][0], s[i][1]), fmaxf(s[i][2], s[i][3]));
      mx = fmaxf(mx, __shfl_xor(mx, 1, 64));
      mx = fmaxf(mx, __shfl_xor(mx, 2, 64));
      mx = fmaxf(mx, __shfl_xor(mx, 4, 64));
      mx = fmaxf(mx, __shfl_xor(mx, 8, 64));
      float mn = fmaxf(m_[i], mx);
      al[i] = __expf(m_[i] - mn);
      m_[i] = mn;
      float sum = 0.f;
#pragma unroll
      for (int j = 0; j < 4; ++j) {
        float p = __expf(s[i][j] - mn);
        s[i][j] = p;
        sum += p;
      }
      sum += __shfl_xor(sum, 1, 64);
      sum += __shfl_xor(sum, 2, 64);
      sum += __shfl_xor(sum, 4, 64);
      sum += __shfl_xor(sum, 8, 64);
      l_[i] = l_[i] * al[i] + sum;
    }
    __syncthreads();                 // V staged, visible to all

    // ---- P transposed write (wave-private cols) + PV ----
#pragma unroll
    for (int j = 0; j < 4; ++j) {
      float4 pv = {s[0][j], s[1][j], s[2][j], s[3][j]};
      *(float4*)&Ps[4 * tx + j][4 * ty] = pv;
    }
#pragma unroll
    for (int i = 0; i < 4; ++i)
#pragma unroll
      for (int j = 0; j < 4; ++j) o[i][j] *= al[i];
#pragma unroll 8
    for (int c = 0; c < 64; ++c) {
      float4 pv = *(const float4*)&Ps[c][4 * ty];
      float4 vv = *(const float4*)&KVs[c][4 * tx];
      float p_[4] = {pv.x, pv.y, pv.z, pv.w};
      float v_[4] = {vv.x, vv.y, vv.z, vv.w};
#pragma unroll
      for (int i = 0; i < 4; ++i)
#pragma unroll
        for (int j = 0; j < 4; ++j)
          o[i][j] = fmaf(p_[i], v_[j], o[i][j]);
    }

    if (nkb < 0) break;
    __syncthreads();                 // PV reads of KVs done
#pragma unroll
    for (int u = 0; u < 4; ++u) {
      *(float4*)&KVs[sr][sc + 4 * u] = nk[u];    // K_next
      cv[u] = nv[u];
    }
    __syncthreads();                 // K_next visible
  }

  // ---- epilogue: divide by l, split to bf16 hi/lo ----
  size_t dbase = ((size_t)b * 2048 + (size_t)qb * 64) * 512 + h * 64;
#pragma unroll
  for (int i = 0; i < 4; ++i) {
    float inv = 1.f / l_[i];
    ushort4 hv, lv;
    float v0 = o[i][0] * inv, v1 = o[i][1] * inv, v2 = o[i][2] * inv, v3 = o[i][3] * inv;
    hv.x = f2bf(v0); lv.x = f2bf(v0 - bf2f(hv.x));
    hv.y = f2bf(v1); lv.y = f2bf(v1 - bf2f(hv.y));
    hv.z = f2bf(v2); lv.z = f2bf(v2 - bf2f(hv.z));
    hv.w = f2bf(v3); lv.w = f2bf(v3 - bf2f(hv.w));
    size_t idx = dbase + (size_t)(4 * ty + i) * 512 + 4 * tx;
    *(ushort4*)(ctx_hi + idx) = hv;
    *(ushort4*)(ctx_lo + idx) = lv;
  }
}

// ============================================================================
// Fused residual add + LayerNorm over D=512. One block (256 thr) per row.
// SPLIT: additionally emit hi/lo bf16 copies of the output.
// ============================================================================
template<bool SPLIT>
__global__ __launch_bounds__(256) void add_ln(const float* __restrict__ a,
                                              const float* __restrict__ bsrc,
                                              const float* __restrict__ g,
                                              const float* __restrict__ beta,
                                              float* __restrict__ out,
                                              ushortT* __restrict__ ohi,
                                              ushortT* __restrict__ olo) {
  const int row = blockIdx.x;
  const int tid = threadIdx.x;
  const float2* a2 = (const float2*)(a + (size_t)row * 512);
  const float2* b2 = (const float2*)(bsrc + (size_t)row * 512);
  float2 va = a2[tid], vb = b2[tid];
  float x0 = va.x + vb.x, x1 = va.y + vb.y;
  float s = x0 + x1;
  float q = x0 * x0 + x1 * x1;
#pragma unroll
  for (int off = 32; off >= 1; off >>= 1) {
    s += __shfl_xor(s, off, 64);
    q += __shfl_xor(q, off, 64);
  }
  __shared__ float ws[4], wq[4];
  int wid = tid >> 6, lane = tid & 63;
  if (lane == 0) { ws[wid] = s; wq[wid] = q; }
  __syncthreads();
  float ts = ws[0] + ws[1] + ws[2] + ws[3];
  float tq = wq[0] + wq[1] + wq[2] + wq[3];
  float mu = ts * (1.0f / 512.0f);
  float var = tq * (1.0f / 512.0f) - mu * mu;
  float rstd = rsqrtf(var + 1e-5f);
  const float2* g2 = (const float2*)g;
  const float2* be2 = (const float2*)beta;
  float2 vg = g2[tid], vbt = be2[tid];
  float2 r;
  r.x = (x0 - mu) * rstd * vg.x + vbt.x;
  r.y = (x1 - mu) * rstd * vg.y + vbt.y;
  size_t o = (size_t)row * 512 + tid * 2;
  *(float2*)(out + o) = r;
  if (SPLIT) {
    ushort2 h, l;
    h.x = f2bf(r.x); l.x = f2bf(r.x - bf2f(h.x));
    h.y = f2bf(r.y); l.y = f2bf(r.y - bf2f(h.y));
    *(ushort2*)(ohi + o) = h;
    *(ushort2*)(olo + o) = l;
  }
}

// ============================================================================
// Launch. Workspace layout (bytes, peak 146.8 MB < 184.5 MB known-safe):
//   [0, 12.58M)        weight splits (persistent)
//   [12.58M, 29.36M)   xs_hi/lo -> later ctx_hi/lo -> later ff (fp32)
//   [29.36M, 79.69M)   qkv fp32 -> later sa | x1 | x1s_hi | x1s_lo
//   [79.69M, 146.8M)   mid_hi / mid_lo
// ============================================================================
extern "C" void kernel_launch(void* const* d_in, const int* in_sizes, int n_in,
                              void* d_out, int out_size, void* d_ws, size_t ws_size,
                              hipStream_t stream) {
  const float* x     = (const float*)d_in[0];
  const float* w_in  = (const float*)d_in[1];
  const float* b_in  = (const float*)d_in[2];
  const float* w_out = (const float*)d_in[3];
  const float* b_out = (const float*)d_in[4];
  const float* w1    = (const float*)d_in[5];
  const float* b1    = (const float*)d_in[6];
  const float* w2    = (const float*)d_in[7];
  const float* b2    = (const float*)d_in[8];
  const float* g1    = (const float*)d_in[9];
  const float* be1   = (const float*)d_in[10];
  const float* g2    = (const float*)d_in[11];
  const float* be2   = (const float*)d_in[12];
  float* out = (float*)d_out;

  char* W = (char*)d_ws;
  // weight splits
  ushortT* wi_h = (ushortT*)(W + 0);             // 1536x512
  ushortT* wi_l = (ushortT*)(W + 1572864);
  ushortT* wo_h = (ushortT*)(W + 3145728);       // 512x512
  ushortT* wo_l = (ushortT*)(W + 3670016);
  ushortT* w1_h = (ushortT*)(W + 4194304);       // 2048x512
  ushortT* w1_l = (ushortT*)(W + 6291456);
  ushortT* w2_h = (ushortT*)(W + 8388608);       // 512x2048
  ushortT* w2_l = (ushortT*)(W + 10485760);
  // region B (16.78 MB): xs -> ctx_s -> ff
  ushortT* xs_h = (ushortT*)(W + 12582912);
  ushortT* xs_l = (ushortT*)(W + 20971520);
  ushortT* ctx_h = xs_h;
  ushortT* ctx_l = xs_l;
  float*   ff    = (float*)(W + 12582912);
  // region C (50.33 MB): qkv -> {sa, x1, x1s}
  float*   qkv  = (float*)(W + 29360128);
  float*   sa   = (float*)(W + 29360128);
  float*   x1   = (float*)(W + 46137344);
  ushortT* x1_h = (ushortT*)(W + 62914560);
  ushortT* x1_l = (ushortT*)(W + 71303168);
  // region D (67.1 MB): mid splits
  ushortT* mid_h = (ushortT*)(W + 79691776);
  ushortT* mid_l = (ushortT*)(W + 113246208);

  dim3 blk(256);

  // 0. splits: x and all weights
  split_bf16<<<dim3(2048), blk, 0, stream>>>(x, xs_h, xs_l, 8192 * 512 / 4);
  split_bf16<<<dim3(768), blk, 0, stream>>>(w_in, wi_h, wi_l, 1536 * 512 / 4);
  split_bf16<<<dim3(256), blk, 0, stream>>>(w_out, wo_h, wo_l, 512 * 512 / 4);
  split_bf16<<<dim3(1024), blk, 0, stream>>>(w1, w1_h, w1_l, 2048 * 512 / 4);
  split_bf16<<<dim3(1024), blk, 0, stream>>>(w2, w2_h, w2_l, 512 * 2048 / 4);

  // 1. qkv = x @ in_proj_w^T + b      [8192,1536] fp32
  gemm_split<0, false><<<dim3(1536 / 128, 8192 / 128), blk, 0, stream>>>(
      xs_h, xs_l, wi_h, wi_l, b_in, qkv, nullptr, nullptr, 1536, 512);
  // 2. attention -> ctx (bf16 hi/lo)
  attn_sparse<<<dim3(32, 8, 4), blk, 0, stream>>>(qkv, ctx_h, ctx_l, kMask);
  // 3. sa = ctx @ out_proj_w^T + b    [8192,512] fp32
  gemm_split<0, false><<<dim3(512 / 128, 8192 / 128), blk, 0, stream>>>(
      ctx_h, ctx_l, wo_h, wo_l, b_out, sa, nullptr, nullptr, 512, 512);
  // 4. x1 = LN(x + sa)  (+ split)
  add_ln<true><<<dim3(8192), blk, 0, stream>>>(x, sa, g1, be1, x1, x1_h, x1_l);
  // 5. mid = relu(x1 @ w1^T + b1)     [8192,2048] bf16 hi/lo
  gemm_split<1, true><<<dim3(2048 / 128, 8192 / 128), blk, 0, stream>>>(
      x1_h, x1_l, w1_h, w1_l, b1, nullptr, mid_h, mid_l, 2048, 512);
  // 6. ff = mid @ w2^T + b2           [8192,512] fp32
  gemm_split<0, false><<<dim3(512 / 128, 8192 / 128), blk, 0, stream>>>(
      mid_h, mid_l, w2_h, w2_l, b2, ff, nullptr, nullptr, 512, 2048);
  // 7. out = LN(x1 + ff)
  add_ln<false><<<dim3(8192), blk, 0, stream>>>(x1, ff, g2, be2, out, nullptr, nullptr);
}

// Round 7
// 548.430 us; speedup vs baseline: 2.4094x; 2.1323x over previous
//
#include <hip/hip_runtime.h>
#include <cmath>
#include <cstdint>

// ============================================================================
// Compile-time replication of the BigBird block mask (np.random.default_rng(0)
// → SeedSequence(0) → PCG64 XSL-RR 128 → choice(32,2,replace=False) per row).
// ============================================================================
typedef unsigned int u32;
typedef unsigned long long u64;
typedef unsigned __int128 u128;

struct MaskBits { u32 row[32]; };

struct Pcg {
  u128 state; u128 inc;
  bool has32; u32 buf32;
};

constexpr u128 pcg_mul() {
  return (((u128)2549297995355413924ULL) << 64) | (u128)4865540595714422341ULL;
}

constexpr u64 pcg_next64(Pcg& s) {
  s.state = s.state * pcg_mul() + s.inc;
  u64 hi = (u64)(s.state >> 64);
  u64 lo = (u64)s.state;
  unsigned rot = (unsigned)(s.state >> 122) & 63u;
  u64 x = hi ^ lo;
  return (x >> rot) | (x << ((64u - rot) & 63u));
}

constexpr u32 pcg_next32(Pcg& s) {
  if (s.has32) { s.has32 = false; return s.buf32; }
  u64 n = pcg_next64(s);
  s.has32 = true; s.buf32 = (u32)(n >> 32);
  return (u32)n;
}

constexpr u32 lemire32(Pcg& s, u32 rng) {
  u32 rng_excl = rng + 1u;
  u64 m = (u64)pcg_next32(s) * (u64)rng_excl;
  u32 leftover = (u32)m;
  if (leftover < rng_excl) {
    u32 threshold = (0xFFFFFFFFu - rng) % rng_excl;
    while (leftover < threshold) {
      m = (u64)pcg_next32(s) * (u64)rng_excl;
      leftover = (u32)m;
    }
  }
  return (u32)(m >> 32);
}

constexpr Pcg pcg_seeded_from_zero() {
  u32 pool[4] = {0, 0, 0, 0};
  u32 hc = 0x43b0d7e5u;                 // INIT_A
  for (int i = 0; i < 4; ++i) {
    u32 v = 0u;
    v ^= hc; hc = hc * 0x931e8875u;     // MULT_A
    v = v * hc; v ^= v >> 16;
    pool[i] = v;
  }
  for (int src = 0; src < 4; ++src) {
    for (int dst = 0; dst < 4; ++dst) {
      if (src == dst) continue;
      u32 v = pool[src];
      v ^= hc; hc = hc * 0x931e8875u;
      v = v * hc; v ^= v >> 16;
      u32 r = (pool[dst] * 0xca01f9ddu) ^ (v * 0x4973f715u);
      r ^= r >> 16;
      pool[dst] = r;
    }
  }
  u32 st[8] = {};
  u32 hb = 0x8b51f9ddu;                 // INIT_B
  for (int i = 0; i < 8; ++i) {
    u32 v = pool[i & 3];
    v ^= hb; hb = hb * 0x58f38dedu;     // MULT_B
    v = v * hb; v ^= v >> 16;
    st[i] = v;
  }
  u64 w0 = (u64)st[0] | ((u64)st[1] << 32);
  u64 w1 = (u64)st[2] | ((u64)st[3] << 32);
  u64 w2 = (u64)st[4] | ((u64)st[5] << 32);
  u64 w3 = (u64)st[6] | ((u64)st[7] << 32);
  u128 initstate = (((u128)w0) << 64) | (u128)w1;
  u128 initseq   = (((u128)w2) << 64) | (u128)w3;
  Pcg s{};
  s.state = 0; s.inc = (initseq << 1) | (u128)1; s.has32 = false; s.buf32 = 0;
  s.state = s.state * pcg_mul() + s.inc;
  s.state += initstate;
  s.state = s.state * pcg_mul() + s.inc;
  return s;
}

constexpr MaskBits make_mask() {
  bool m[32][32] = {};
  for (int i = 0; i < 32; ++i)
    for (int j = 0; j < 32; ++j) {
      int d = i - j; if (d < 0) d = -d;
      m[i][j] = (d <= 1);
    }
  for (int j = 0; j < 32; ++j) m[0][j] = true;
  for (int i = 0; i < 32; ++i) m[i][0] = true;
  Pcg s = pcg_seeded_from_zero();
  for (int r = 0; r < 32; ++r) {
    u64 hs[4] = {~0ull, ~0ull, ~0ull, ~0ull};
    u64 idx[2] = {0, 0};
    for (int j = 30; j <= 31; ++j) {
      u64 val = (u64)lemire32(s, (u32)j);
      u64 loc = val & 3u;
      while (hs[loc] != ~0ull && hs[loc] != val) loc = (loc + 1) & 3u;
      if (hs[loc] == ~0ull) { hs[loc] = val; idx[j - 30] = val; }
      else {
        loc = (u64)j & 3u;
        while (hs[loc] != ~0ull) loc = (loc + 1) & 3u;
        hs[loc] = (u64)j; idx[j - 30] = (u64)j;
      }
    }
    u32 jj = lemire32(s, 1u);
    u64 t = idx[1]; idx[1] = idx[jj]; idx[jj] = t;
    m[r][(int)idx[0]] = true;
    m[r][(int)idx[1]] = true;
  }
  MaskBits mb{};
  for (int i = 0; i < 32; ++i) {
    u32 bits = 0;
    for (int j = 0; j < 32; ++j) if (m[i][j]) bits |= (1u << j);
    mb.row[i] = bits;
  }
  return mb;
}

static constexpr MaskBits kMask = make_mask();

// ============================================================================
// bf16 helpers (RTNE), header-free
// ============================================================================
typedef unsigned short ushortT;
typedef __attribute__((ext_vector_type(8))) short short8;     // MFMA A/B frag
typedef __attribute__((ext_vector_type(8))) unsigned short ushort8;
typedef __attribute__((ext_vector_type(4))) float f32x4;      // MFMA C/D frag

__device__ __forceinline__ ushortT f2bf(float x) {
  u32 u = __float_as_uint(x);
  return (ushortT)((u + 0x7fffu + ((u >> 16) & 1u)) >> 16);
}
__device__ __forceinline__ float bf2f(ushortT h) {
  return __uint_as_float(((u32)h) << 16);
}

// ============================================================================
// Elementwise fp32 -> (hi,lo) bf16 split. Grid-stride over float4 quads.
// ============================================================================
__global__ __launch_bounds__(256) void split_bf16(const float* __restrict__ src,
                                                  ushortT* __restrict__ hi,
                                                  ushortT* __restrict__ lo,
                                                  int n4) {
  for (int i = blockIdx.x * 256 + threadIdx.x; i < n4; i += gridDim.x * 256) {
    float4 v = ((const float4*)src)[i];
    ushort4 h, l;
    h.x = f2bf(v.x); l.x = f2bf(v.x - bf2f(h.x));
    h.y = f2bf(v.y); l.y = f2bf(v.y - bf2f(h.y));
    h.z = f2bf(v.z); l.z = f2bf(v.z - bf2f(h.z));
    h.w = f2bf(v.w); l.w = f2bf(v.w - bf2f(h.w));
    ((ushort4*)hi)[i] = h;
    ((ushort4*)lo)[i] = l;
  }
}

// ============================================================================
// Split-bf16 MFMA GEMM:  C[M,N] = A[M,K]·W[N,K]^T + bias
// ATERMS=3: Markidis (ah·bh + al·bh + ah·bl).  ATERMS=2: ah·bh + ah·bl.
// 128x128 tile, BK=32, 4 waves (2x2 of 64x64). LDS k-group XOR swizzle.
// EPI: 0 = fp32 out; 1 = split hi/lo bf16 out; 2 = single bf16 out.
// ============================================================================
template<int ATERMS, int EPI, bool RELU>
__global__ __launch_bounds__(256) void gemm_split(
    const ushortT* __restrict__ Ahi, const ushortT* __restrict__ Alo,
    const ushortT* __restrict__ Bhi, const ushortT* __restrict__ Blo,
    const float* __restrict__ bias,
    float* __restrict__ C, ushortT* __restrict__ Chi, ushortT* __restrict__ Clo,
    int N, int K) {
  constexpr int NT = (ATERMS == 3) ? 4 : 3;
  __shared__ ushortT lds[NT][128 * 32];

  const int tid = threadIdx.x;
  const int l = tid & 63;
  const int wid = tid >> 6;
  const int wr = wid >> 1, wc = wid & 1;          // 2x2 wave grid
  const int bm = blockIdx.y * 128, bn = blockIdx.x * 128;

  const int srow = tid >> 1;                      // staging row 0..127
  const int sh = tid & 1;                         // staging half (16 el)

  f32x4 acc[4][4] = {};

  const ushortT* srcs[NT];
  if constexpr (ATERMS == 3) {
    srcs[0] = Ahi + (size_t)bm * K;
    srcs[1] = Alo + (size_t)bm * K;
    srcs[2] = Bhi + (size_t)bn * K;
    srcs[3] = Blo + (size_t)bn * K;
  } else {
    srcs[0] = Ahi + (size_t)bm * K;
    srcs[1] = Bhi + (size_t)bn * K;
    srcs[2] = Blo + (size_t)bn * K;
  }

  const int swz = (srow >> 1) & 3;                // staging swizzle key

  for (int kc = 0; kc < K; kc += 32) {
    // ---- global loads to regs (2 x 16B per tile per thread) ----
    ushort8 stg[NT][2];
#pragma unroll
    for (int t = 0; t < NT; ++t) {
      const ushortT* p = srcs[t] + (size_t)srow * K + kc + sh * 16;
      stg[t][0] = *(const ushort8*)p;
      stg[t][1] = *(const ushort8*)(p + 8);
    }
    __syncthreads();     // previous chunk's fragment reads complete
#pragma unroll
    for (int t = 0; t < NT; ++t) {
#pragma unroll
      for (int g2 = 0; g2 < 2; ++g2) {
        int g = 2 * sh + g2;
        int slot = g ^ swz;
        *(ushort8*)&lds[t][srow * 32 + slot * 8] = stg[t][g2];
      }
    }
    __syncthreads();

    // ---- fragment reads + MFMA ----
    short8 ah[4], al_[4], bh[4], bl[4];
    const int g = l >> 4;
    const int rl = l & 15;
#pragma unroll
    for (int m = 0; m < 4; ++m) {
      int ra = wr * 64 + m * 16 + rl;
      int idx = ra * 32 + (g ^ ((ra >> 1) & 3)) * 8;
      ah[m] = *(const short8*)&lds[0][idx];
      if constexpr (ATERMS == 3) al_[m] = *(const short8*)&lds[1][idx];
    }
#pragma unroll
    for (int n = 0; n < 4; ++n) {
      int rb = wc * 64 + n * 16 + rl;
      int idx = rb * 32 + (g ^ ((rb >> 1) & 3)) * 8;
      bh[n] = *(const short8*)&lds[NT - 2][idx];
      bl[n] = *(const short8*)&lds[NT - 1][idx];
    }
#pragma unroll
    for (int m = 0; m < 4; ++m)
#pragma unroll
      for (int n = 0; n < 4; ++n) {
        acc[m][n] = __builtin_amdgcn_mfma_f32_16x16x32_bf16(ah[m], bh[n], acc[m][n], 0, 0, 0);
        if constexpr (ATERMS == 3)
          acc[m][n] = __builtin_amdgcn_mfma_f32_16x16x32_bf16(al_[m], bh[n], acc[m][n], 0, 0, 0);
        acc[m][n] = __builtin_amdgcn_mfma_f32_16x16x32_bf16(ah[m], bl[n], acc[m][n], 0, 0, 0);
      }
  }

  // ---- epilogue: C/D layout col = lane&15, row = (lane>>4)*4 + reg ----
  const int cg = l & 15;
#pragma unroll
  for (int m = 0; m < 4; ++m)
#pragma unroll
    for (int n = 0; n < 4; ++n) {
      int col = bn + wc * 64 + n * 16 + cg;
      float bb = bias[col];
#pragma unroll
      for (int r = 0; r < 4; ++r) {
        int row = bm + wr * 64 + m * 16 + (l >> 4) * 4 + r;
        float v = acc[m][n][r] + bb;
        if (RELU) v = fmaxf(v, 0.f);
        size_t o = (size_t)row * N + col;
        if constexpr (EPI == 0) {
          C[o] = v;
        } else if constexpr (EPI == 1) {
          ushortT hh = f2bf(v);
          Chi[o] = hh;
          Clo[o] = f2bf(v - bf2f(hh));
        } else {
          Chi[o] = f2bf(v);
        }
      }
    }
}

// ============================================================================
// Block-sparse flash attention, v4: MFMA-based.
// One block (256 thr, 4 waves) per (qblock, head, batch). Wave w owns q rows
// 16w..16w+15. Inputs are pre-split bf16 hi/lo (from the qkv GEMM epilogue).
// LDS (pitch 72 bf16 = 144 B, 16B-aligned rows, ~2-way banking):
//   Qh/Ql/Kh/Kl row-major [64 rows][d], V transposed Vt[d][key] (hi/lo),
//   P per-wave [16 q][64 key] bf16.
// QK^T: 3-term Markidis, 24 MFMA/wave/iter. Softmax in registers (16-lane
// shfl_xor groups), 1/sqrt(64) folded into scores in fp32 (exact). PV: P bf16
// x (Vh+Vl), 16 MFMA/wave/iter. 2 barriers/iter. No register prefetch.
// ============================================================================
__global__ __launch_bounds__(256, 2) void attn_mfma(const ushortT* __restrict__ qkv_h,
                                                    const ushortT* __restrict__ qkv_l,
                                                    ushortT* __restrict__ ctx_hi,
                                                    ushortT* __restrict__ ctx_lo,
                                                    MaskBits mask) {
  constexpr int LP = 72;                 // LDS pitch in bf16 (144 B, 16B-aligned)
  __shared__ ushortT Qh[64][LP], Ql[64][LP];
  __shared__ ushortT Kh[64][LP], Kl[64][LP];
  __shared__ ushortT Vth[64][LP], Vtl[64][LP];   // [d][key]
  __shared__ ushortT Pw[4][16][LP];              // per-wave [q][key]

  const int qb = blockIdx.x, hd = blockIdx.y, b = blockIdx.z;
  const int tid = threadIdx.x;
  const int w = tid >> 6;
  const int l = tid & 63;
  const int g = l >> 4;                  // k-group 0..3
  const int rl = l & 15;                 // row/col within 16
  const size_t RS = 1536;

  const ushortT* qbase_h = qkv_h + ((size_t)b * 2048 + (size_t)qb * 64) * RS + hd * 64;
  const ushortT* qbase_l = qkv_l + ((size_t)b * 2048 + (size_t)qb * 64) * RS + hd * 64;
  const ushortT* kbase_h = qkv_h + (size_t)b * 2048 * RS + 512 + hd * 64;
  const ushortT* kbase_l = qkv_l + (size_t)b * 2048 * RS + 512 + hd * 64;
  const ushortT* vbase_h = qkv_h + (size_t)b * 2048 * RS + 1024 + hd * 64;
  const ushortT* vbase_l = qkv_l + (size_t)b * 2048 * RS + 1024 + hd * 64;

  // staging coords
  const int kr = tid >> 2;               // row 0..63
  const int kc = (tid & 3) * 16;         // col chunk
  const int k0 = (tid & 15) * 4;         // V: 4 keys
  const int dg = (tid >> 4) * 4;         // V: 4 d's

  { // stage Q hi/lo (row-major)
    const ushortT* ph = qbase_h + (size_t)kr * RS + kc;
    const ushortT* pl = qbase_l + (size_t)kr * RS + kc;
    *(ushort8*)&Qh[kr][kc]     = *(const ushort8*)ph;
    *(ushort8*)&Qh[kr][kc + 8] = *(const ushort8*)(ph + 8);
    *(ushort8*)&Ql[kr][kc]     = *(const ushort8*)pl;
    *(ushort8*)&Ql[kr][kc + 8] = *(const ushort8*)(pl + 8);
  }

  float m_[4] = {-INFINITY, -INFINITY, -INFINITY, -INFINITY};
  float l_[4] = {0.f, 0.f, 0.f, 0.f};
  f32x4 acc[4] = {};                     // O strip: [ntile d][4 q-rows]

  u32 rem = mask.row[qb];
  while (rem) {
    const int kb = (int)__builtin_ctz(rem);
    rem &= rem - 1u;

    // ---- global loads (K rows, V 4x4 sub-block) ----
    const ushortT* ph = kbase_h + (size_t)(kb * 64 + kr) * RS + kc;
    const ushortT* pl = kbase_l + (size_t)(kb * 64 + kr) * RS + kc;
    ushort8 kh0 = *(const ushort8*)ph, kh1 = *(const ushort8*)(ph + 8);
    ushort8 kl0 = *(const ushort8*)pl, kl1 = *(const ushort8*)(pl + 8);
    ushortT vbh[4][4], vbl[4][4];
#pragma unroll
    for (int i = 0; i < 4; ++i) {
      const ushortT* pvh = vbase_h + (size_t)(kb * 64 + k0 + i) * RS + dg;
      const ushortT* pvl = vbase_l + (size_t)(kb * 64 + k0 + i) * RS + dg;
      *(ushort4*)vbh[i] = *(const ushort4*)pvh;
      *(ushort4*)vbl[i] = *(const ushort4*)pvl;
    }

    __syncthreads();                     // all waves done reading prev K/Vt

    // ---- LDS writes: K row-major, V transposed ----
    *(ushort8*)&Kh[kr][kc]     = kh0;
    *(ushort8*)&Kh[kr][kc + 8] = kh1;
    *(ushort8*)&Kl[kr][kc]     = kl0;
    *(ushort8*)&Kl[kr][kc + 8] = kl1;
#pragma unroll
    for (int dd = 0; dd < 4; ++dd) {
      ushort4 oh = {vbh[0][dd], vbh[1][dd], vbh[2][dd], vbh[3][dd]};
      ushort4 ol = {vbl[0][dd], vbl[1][dd], vbl[2][dd], vbl[3][dd]};
      *(ushort4*)&Vth[dg + dd][k0] = oh;
      *(ushort4*)&Vtl[dg + dd][k0] = ol;
    }
    __syncthreads();

    // ---- QK^T: 3-term, acc strips of 16 keys ----
    short8 qah[2], qal[2];
#pragma unroll
    for (int ds = 0; ds < 2; ++ds) {
      qah[ds] = *(const short8*)&Qh[16 * w + rl][ds * 32 + g * 8];
      qal[ds] = *(const short8*)&Ql[16 * w + rl][ds * 32 + g * 8];
    }
    f32x4 sc[4] = {};
#pragma unroll
    for (int t = 0; t < 4; ++t) {
#pragma unroll
      for (int ds = 0; ds < 2; ++ds) {
        short8 kbh = *(const short8*)&Kh[16 * t + rl][ds * 32 + g * 8];
        short8 kbl = *(const short8*)&Kl[16 * t + rl][ds * 32 + g * 8];
        sc[t] = __builtin_amdgcn_mfma_f32_16x16x32_bf16(qah[ds], kbh, sc[t], 0, 0, 0);
        sc[t] = __builtin_amdgcn_mfma_f32_16x16x32_bf16(qal[ds], kbh, sc[t], 0, 0, 0);
        sc[t] = __builtin_amdgcn_mfma_f32_16x16x32_bf16(qah[ds], kbl, sc[t], 0, 0, 0);
      }
    }

    // ---- register online softmax (rows g*4+r, cols t*16+rl) ----
    float al[4];
#pragma unroll
    for (int r = 0; r < 4; ++r) {
      float s0 = sc[0][r] * 0.125f, s1 = sc[1][r] * 0.125f;
      float s2 = sc[2][r] * 0.125f, s3 = sc[3][r] * 0.125f;
      float mx = fmaxf(fmaxf(s0, s1), fmaxf(s2, s3));
      mx = fmaxf(mx, __shfl_xor(mx, 1, 64));
      mx = fmaxf(mx, __shfl_xor(mx, 2, 64));
      mx = fmaxf(mx, __shfl_xor(mx, 4, 64));
      mx = fmaxf(mx, __shfl_xor(mx, 8, 64));
      float mn = fmaxf(m_[r], mx);
      al[r] = __expf(m_[r] - mn);        // 0 on first block
      m_[r] = mn;
      float p0 = __expf(s0 - mn), p1 = __expf(s1 - mn);
      float p2 = __expf(s2 - mn), p3 = __expf(s3 - mn);
      float sum = p0 + p1 + p2 + p3;
      sum += __shfl_xor(sum, 1, 64);
      sum += __shfl_xor(sum, 2, 64);
      sum += __shfl_xor(sum, 4, 64);
      sum += __shfl_xor(sum, 8, 64);
      l_[r] = l_[r] * al[r] + sum;
      // P -> bf16, wave-private LDS strip [q row][key col]
      Pw[w][g * 4 + r][0 * 16 + rl] = f2bf(p0);
      Pw[w][g * 4 + r][1 * 16 + rl] = f2bf(p1);
      Pw[w][g * 4 + r][2 * 16 + rl] = f2bf(p2);
      Pw[w][g * 4 + r][3 * 16 + rl] = f2bf(p3);
    }

    // ---- rescale O ----
#pragma unroll
    for (int nt = 0; nt < 4; ++nt)
#pragma unroll
      for (int r = 0; r < 4; ++r) acc[nt][r] *= al[r];

    // ---- PV: O += P · (Vh + Vl)  (wave-private P, same-wave ds order) ----
    short8 pa[2];
#pragma unroll
    for (int ks = 0; ks < 2; ++ks)
      pa[ks] = *(const short8*)&Pw[w][rl][ks * 32 + g * 8];
#pragma unroll
    for (int nt = 0; nt < 4; ++nt) {
#pragma unroll
      for (int ks = 0; ks < 2; ++ks) {
        short8 vh = *(const short8*)&Vth[nt * 16 + rl][ks * 32 + g * 8];
        short8 vl = *(const short8*)&Vtl[nt * 16 + rl][ks * 32 + g * 8];
        acc[nt] = __builtin_amdgcn_mfma_f32_16x16x32_bf16(pa[ks], vh, acc[nt], 0, 0, 0);
        acc[nt] = __builtin_amdgcn_mfma_f32_16x16x32_bf16(pa[ks], vl, acc[nt], 0, 0, 0);
      }
    }
  }

  // ---- epilogue: divide by l, split hi/lo bf16 ----
  float inv[4];
#pragma unroll
  for (int r = 0; r < 4; ++r) inv[r] = 1.f / l_[r];
  size_t obase = ((size_t)b * 2048 + (size_t)qb * 64 + 16 * w + g * 4) * 512 + hd * 64 + rl;
#pragma unroll
  for (int nt = 0; nt < 4; ++nt)
#pragma unroll
    for (int r = 0; r < 4; ++r) {
      float v = acc[nt][r] * inv[r];
      ushortT hh = f2bf(v);
      size_t o = obase + (size_t)r * 512 + nt * 16;
      ctx_hi[o] = hh;
      ctx_lo[o] = f2bf(v - bf2f(hh));
    }
}

// ============================================================================
// Fused residual add + LayerNorm over D=512. One block (256 thr) per row.
// SPLIT: additionally emit hi/lo bf16 copies of the output.
// ============================================================================
template<bool SPLIT>
__global__ __launch_bounds__(256) void add_ln(const float* __restrict__ a,
                                              const float* __restrict__ bsrc,
                                              const float* __restrict__ g,
                                              const float* __restrict__ beta,
                                              float* __restrict__ out,
                                              ushortT* __restrict__ ohi,
                                              ushortT* __restrict__ olo) {
  const int row = blockIdx.x;
  const int tid = threadIdx.x;
  const float2* a2 = (const float2*)(a + (size_t)row * 512);
  const float2* b2 = (const float2*)(bsrc + (size_t)row * 512);
  float2 va = a2[tid], vb = b2[tid];
  float x0 = va.x + vb.x, x1 = va.y + vb.y;
  float s = x0 + x1;
  float q = x0 * x0 + x1 * x1;
#pragma unroll
  for (int off = 32; off >= 1; off >>= 1) {
    s += __shfl_xor(s, off, 64);
    q += __shfl_xor(q, off, 64);
  }
  __shared__ float ws[4], wq[4];
  int wid = tid >> 6, lane = tid & 63;
  if (lane == 0) { ws[wid] = s; wq[wid] = q; }
  __syncthreads();
  float ts = ws[0] + ws[1] + ws[2] + ws[3];
  float tq = wq[0] + wq[1] + wq[2] + wq[3];
  float mu = ts * (1.0f / 512.0f);
  float var = tq * (1.0f / 512.0f) - mu * mu;
  float rstd = rsqrtf(var + 1e-5f);
  const float2* g2 = (const float2*)g;
  const float2* be2 = (const float2*)beta;
  float2 vg = g2[tid], vbt = be2[tid];
  float2 r;
  r.x = (x0 - mu) * rstd * vg.x + vbt.x;
  r.y = (x1 - mu) * rstd * vg.y + vbt.y;
  size_t o = (size_t)row * 512 + tid * 2;
  *(float2*)(out + o) = r;
  if (SPLIT) {
    ushort2 h, l;
    h.x = f2bf(r.x); l.x = f2bf(r.x - bf2f(h.x));
    h.y = f2bf(r.y); l.y = f2bf(r.y - bf2f(h.y));
    *(ushort2*)(ohi + o) = h;
    *(ushort2*)(olo + o) = l;
  }
}

// ============================================================================
// Launch. Workspace (bytes, total 130.0 MB < 147 MB verified):
//   A [0, 12.58M)          weight splits (persistent)
//   B [12.58M, 29.36M)     xs_h/l -> ctx_h/l
//   C [29.36M, 79.69M)     qkv_h/l -> {sa|ff, x1_h, x1_l}
//   D [79.69M, 96.47M)     x1 fp32
//   E [96.47M, 130.02M)    mid (single bf16)
// ============================================================================
extern "C" void kernel_launch(void* const* d_in, const int* in_sizes, int n_in,
                              void* d_out, int out_size, void* d_ws, size_t ws_size,
                              hipStream_t stream) {
  const float* x     = (const float*)d_in[0];
  const float* w_in  = (const float*)d_in[1];
  const float* b_in  = (const float*)d_in[2];
  const float* w_out = (const float*)d_in[3];
  const float* b_out = (const float*)d_in[4];
  const float* w1    = (const float*)d_in[5];
  const float* b1    = (const float*)d_in[6];
  const float* w2    = (const float*)d_in[7];
  const float* b2    = (const float*)d_in[8];
  const float* g1    = (const float*)d_in[9];
  const float* be1   = (const float*)d_in[10];
  const float* g2    = (const float*)d_in[11];
  const float* be2   = (const float*)d_in[12];
  float* out = (float*)d_out;

  char* W = (char*)d_ws;
  // A: weight splits
  ushortT* wi_h = (ushortT*)(W + 0);             // 1536x512
  ushortT* wi_l = (ushortT*)(W + 1572864);
  ushortT* wo_h = (ushortT*)(W + 3145728);       // 512x512
  ushortT* wo_l = (ushortT*)(W + 3670016);
  ushortT* w1_h = (ushortT*)(W + 4194304);       // 2048x512
  ushortT* w1_l = (ushortT*)(W + 6291456);
  ushortT* w2_h = (ushortT*)(W + 8388608);       // 512x2048
  ushortT* w2_l = (ushortT*)(W + 10485760);
  // B: xs -> ctx
  ushortT* xs_h = (ushortT*)(W + 12582912);
  ushortT* xs_l = (ushortT*)(W + 20971520);
  ushortT* ctx_h = xs_h;
  ushortT* ctx_l = xs_l;
  // C: qkv_h/l -> {sa|ff, x1_h, x1_l}
  ushortT* qkv_h = (ushortT*)(W + 29360128);     // 8192x1536 bf16
  ushortT* qkv_l = (ushortT*)(W + 54525952);
  float*   sa    = (float*)(W + 29360128);       // 8192x512 fp32
  float*   ff    = (float*)(W + 29360128);
  ushortT* x1_h  = (ushortT*)(W + 46137344);
  ushortT* x1_l  = (ushortT*)(W + 54525952);
  // D: x1 fp32
  float*   x1    = (float*)(W + 79691776);
  // E: mid single bf16
  ushortT* mid   = (ushortT*)(W + 96468992);     // 8192x2048 bf16

  dim3 blk(256);

  // 0. splits: x and all weights
  split_bf16<<<dim3(2048), blk, 0, stream>>>(x, xs_h, xs_l, 8192 * 512 / 4);
  split_bf16<<<dim3(768), blk, 0, stream>>>(w_in, wi_h, wi_l, 1536 * 512 / 4);
  split_bf16<<<dim3(256), blk, 0, stream>>>(w_out, wo_h, wo_l, 512 * 512 / 4);
  split_bf16<<<dim3(1024), blk, 0, stream>>>(w1, w1_h, w1_l, 2048 * 512 / 4);
  split_bf16<<<dim3(1024), blk, 0, stream>>>(w2, w2_h, w2_l, 512 * 2048 / 4);

  // 1. qkv = x @ in_proj_w^T + b      [8192,1536] -> split bf16 hi/lo
  gemm_split<3, 1, false><<<dim3(1536 / 128, 8192 / 128), blk, 0, stream>>>(
      xs_h, xs_l, wi_h, wi_l, b_in, nullptr, qkv_h, qkv_l, 1536, 512);
  // 2. MFMA block-sparse attention -> ctx (bf16 hi/lo)
  attn_mfma<<<dim3(32, 8, 4), blk, 0, stream>>>(qkv_h, qkv_l, ctx_h, ctx_l, kMask);
  // 3. sa = ctx @ out_proj_w^T + b    [8192,512] fp32
  gemm_split<3, 0, false><<<dim3(512 / 128, 8192 / 128), blk, 0, stream>>>(
      ctx_h, ctx_l, wo_h, wo_l, b_out, sa, nullptr, nullptr, 512, 512);
  // 4. x1 = LN(x + sa)  (+ split)
  add_ln<true><<<dim3(8192), blk, 0, stream>>>(x, sa, g1, be1, x1, x1_h, x1_l);
  // 5. mid = relu(x1 @ w1^T + b1)     [8192,2048] single bf16
  gemm_split<3, 2, true><<<dim3(2048 / 128, 8192 / 128), blk, 0, stream>>>(
      x1_h, x1_l, w1_h, w1_l, b1, nullptr, mid, nullptr, 2048, 512);
  // 6. ff = mid @ w2^T + b2           [8192,512] fp32 (2-term: A single bf16)
  gemm_split<2, 0, false><<<dim3(512 / 128, 8192 / 128), blk, 0, stream>>>(
      mid, nullptr, w2_h, w2_l, b2, ff, nullptr, nullptr, 512, 2048);
  // 7. out = LN(x1 + ff)
  add_ln<false><<<dim3(8192), blk, 0, stream>>>(x1, ff, g2, be2, out, nullptr, nullptr);
}

// Round 10
// 384.927 us; speedup vs baseline: 3.4328x; 1.4248x over previous
//
#include <hip/hip_runtime.h>
#include <cmath>
#include <cstdint>

// ============================================================================
// Compile-time replication of the BigBird block mask (np.random.default_rng(0)
// → SeedSequence(0) → PCG64 XSL-RR 128 → choice(32,2,replace=False) per row).
// ============================================================================
typedef unsigned int u32;
typedef unsigned long long u64;
typedef unsigned __int128 u128;

struct MaskBits { u32 row[32]; };

struct Pcg {
  u128 state; u128 inc;
  bool has32; u32 buf32;
};

constexpr u128 pcg_mul() {
  return (((u128)2549297995355413924ULL) << 64) | (u128)4865540595714422341ULL;
}

constexpr u64 pcg_next64(Pcg& s) {
  s.state = s.state * pcg_mul() + s.inc;
  u64 hi = (u64)(s.state >> 64);
  u64 lo = (u64)s.state;
  unsigned rot = (unsigned)(s.state >> 122) & 63u;
  u64 x = hi ^ lo;
  return (x >> rot) | (x << ((64u - rot) & 63u));
}

constexpr u32 pcg_next32(Pcg& s) {
  if (s.has32) { s.has32 = false; return s.buf32; }
  u64 n = pcg_next64(s);
  s.has32 = true; s.buf32 = (u32)(n >> 32);
  return (u32)n;
}

constexpr u32 lemire32(Pcg& s, u32 rng) {
  u32 rng_excl = rng + 1u;
  u64 m = (u64)pcg_next32(s) * (u64)rng_excl;
  u32 leftover = (u32)m;
  if (leftover < rng_excl) {
    u32 threshold = (0xFFFFFFFFu - rng) % rng_excl;
    while (leftover < threshold) {
      m = (u64)pcg_next32(s) * (u64)rng_excl;
      leftover = (u32)m;
    }
  }
  return (u32)(m >> 32);
}

constexpr Pcg pcg_seeded_from_zero() {
  u32 pool[4] = {0, 0, 0, 0};
  u32 hc = 0x43b0d7e5u;                 // INIT_A
  for (int i = 0; i < 4; ++i) {
    u32 v = 0u;
    v ^= hc; hc = hc * 0x931e8875u;     // MULT_A
    v = v * hc; v ^= v >> 16;
    pool[i] = v;
  }
  for (int src = 0; src < 4; ++src) {
    for (int dst = 0; dst < 4; ++dst) {
      if (src == dst) continue;
      u32 v = pool[src];
      v ^= hc; hc = hc * 0x931e8875u;
      v = v * hc; v ^= v >> 16;
      u32 r = (pool[dst] * 0xca01f9ddu) ^ (v * 0x4973f715u);
      r ^= r >> 16;
      pool[dst] = r;
    }
  }
  u32 st[8] = {};
  u32 hb = 0x8b51f9ddu;                 // INIT_B
  for (int i = 0; i < 8; ++i) {
    u32 v = pool[i & 3];
    v ^= hb; hb = hb * 0x58f38dedu;     // MULT_B
    v = v * hb; v ^= v >> 16;
    st[i] = v;
  }
  u64 w0 = (u64)st[0] | ((u64)st[1] << 32);
  u64 w1 = (u64)st[2] | ((u64)st[3] << 32);
  u64 w2 = (u64)st[4] | ((u64)st[5] << 32);
  u64 w3 = (u64)st[6] | ((u64)st[7] << 32);
  u128 initstate = (((u128)w0) << 64) | (u128)w1;
  u128 initseq   = (((u128)w2) << 64) | (u128)w3;
  Pcg s{};
  s.state = 0; s.inc = (initseq << 1) | (u128)1; s.has32 = false; s.buf32 = 0;
  s.state = s.state * pcg_mul() + s.inc;
  s.state += initstate;
  s.state = s.state * pcg_mul() + s.inc;
  return s;
}

constexpr MaskBits make_mask() {
  bool m[32][32] = {};
  for (int i = 0; i < 32; ++i)
    for (int j = 0; j < 32; ++j) {
      int d = i - j; if (d < 0) d = -d;
      m[i][j] = (d <= 1);
    }
  for (int j = 0; j < 32; ++j) m[0][j] = true;
  for (int i = 0; i < 32; ++i) m[i][0] = true;
  Pcg s = pcg_seeded_from_zero();
  for (int r = 0; r < 32; ++r) {
    u64 hs[4] = {~0ull, ~0ull, ~0ull, ~0ull};
    u64 idx[2] = {0, 0};
    for (int j = 30; j <= 31; ++j) {
      u64 val = (u64)lemire32(s, (u32)j);
      u64 loc = val & 3u;
      while (hs[loc] != ~0ull && hs[loc] != val) loc = (loc + 1) & 3u;
      if (hs[loc] == ~0ull) { hs[loc] = val; idx[j - 30] = val; }
      else {
        loc = (u64)j & 3u;
        while (hs[loc] != ~0ull) loc = (loc + 1) & 3u;
        hs[loc] = (u64)j; idx[j - 30] = (u64)j;
      }
    }
    u32 jj = lemire32(s, 1u);
    u64 t = idx[1]; idx[1] = idx[jj]; idx[jj] = t;
    m[r][(int)idx[0]] = true;
    m[r][(int)idx[1]] = true;
  }
  MaskBits mb{};
  for (int i = 0; i < 32; ++i) {
    u32 bits = 0;
    for (int j = 0; j < 32; ++j) if (m[i][j]) bits |= (1u << j);
    mb.row[i] = bits;
  }
  return mb;
}

static constexpr MaskBits kMask = make_mask();

// ============================================================================
// bf16 helpers (RTNE), header-free
// ============================================================================
typedef unsigned short ushortT;
typedef __attribute__((ext_vector_type(8))) short short8;     // MFMA A/B frag
typedef __attribute__((ext_vector_type(8))) unsigned short ushort8;
typedef __attribute__((ext_vector_type(4))) float f32x4;      // MFMA C/D frag

__device__ __forceinline__ ushortT f2bf(float x) {
  u32 u = __float_as_uint(x);
  return (ushortT)((u + 0x7fffu + ((u >> 16) & 1u)) >> 16);
}
__device__ __forceinline__ float bf2f(ushortT h) {
  return __uint_as_float(((u32)h) << 16);
}

// ============================================================================
// Elementwise fp32 -> (hi,lo) bf16 split. Grid-stride over float4 quads.
// ============================================================================
__global__ __launch_bounds__(256) void split_bf16(const float* __restrict__ src,
                                                  ushortT* __restrict__ hi,
                                                  ushortT* __restrict__ lo,
                                                  int n4) {
  for (int i = blockIdx.x * 256 + threadIdx.x; i < n4; i += gridDim.x * 256) {
    float4 v = ((const float4*)src)[i];
    ushort4 h, l;
    h.x = f2bf(v.x); l.x = f2bf(v.x - bf2f(h.x));
    h.y = f2bf(v.y); l.y = f2bf(v.y - bf2f(h.y));
    h.z = f2bf(v.z); l.z = f2bf(v.z - bf2f(h.z));
    h.w = f2bf(v.w); l.w = f2bf(v.w - bf2f(h.w));
    ((ushort4*)hi)[i] = h;
    ((ushort4*)lo)[i] = l;
  }
}

// ============================================================================
// Split-bf16 MFMA GEMM:  C[M,N] = A[M,K]·W[N,K]^T + bias
// ATERMS=3: Markidis (ah·bh + al·bh + ah·bl).  ATERMS=2: ah·bh + ah·bl.
// 128x128 tile, BK=32, 4 waves (2x2 of 64x64). LDS k-group XOR swizzle.
// EPI: 0 = fp32 out; 1 = split hi/lo bf16 out; 2 = single bf16 out.
// ============================================================================
template<int ATERMS, int EPI, bool RELU>
__global__ __launch_bounds__(256) void gemm_split(
    const ushortT* __restrict__ Ahi, const ushortT* __restrict__ Alo,
    const ushortT* __restrict__ Bhi, const ushortT* __restrict__ Blo,
    const float* __restrict__ bias,
    float* __restrict__ C, ushortT* __restrict__ Chi, ushortT* __restrict__ Clo,
    int N, int K) {
  constexpr int NT = (ATERMS == 3) ? 4 : 3;
  __shared__ ushortT lds[NT][128 * 32];

  const int tid = threadIdx.x;
  const int l = tid & 63;
  const int wid = tid >> 6;
  const int wr = wid >> 1, wc = wid & 1;          // 2x2 wave grid
  const int bm = blockIdx.y * 128, bn = blockIdx.x * 128;

  const int srow = tid >> 1;                      // staging row 0..127
  const int sh = tid & 1;                         // staging half (16 el)

  f32x4 acc[4][4] = {};

  const ushortT* srcs[NT];
  if constexpr (ATERMS == 3) {
    srcs[0] = Ahi + (size_t)bm * K;
    srcs[1] = Alo + (size_t)bm * K;
    srcs[2] = Bhi + (size_t)bn * K;
    srcs[3] = Blo + (size_t)bn * K;
  } else {
    srcs[0] = Ahi + (size_t)bm * K;
    srcs[1] = Bhi + (size_t)bn * K;
    srcs[2] = Blo + (size_t)bn * K;
  }

  const int swz = (srow >> 1) & 3;                // staging swizzle key

  for (int kc = 0; kc < K; kc += 32) {
    // ---- global loads to regs (2 x 16B per tile per thread) ----
    ushort8 stg[NT][2];
#pragma unroll
    for (int t = 0; t < NT; ++t) {
      const ushortT* p = srcs[t] + (size_t)srow * K + kc + sh * 16;
      stg[t][0] = *(const ushort8*)p;
      stg[t][1] = *(const ushort8*)(p + 8);
    }
    __syncthreads();     // previous chunk's fragment reads complete
#pragma unroll
    for (int t = 0; t < NT; ++t) {
#pragma unroll
      for (int g2 = 0; g2 < 2; ++g2) {
        int g = 2 * sh + g2;
        int slot = g ^ swz;
        *(ushort8*)&lds[t][srow * 32 + slot * 8] = stg[t][g2];
      }
    }
    __syncthreads();

    // ---- fragment reads + MFMA ----
    short8 ah[4], al_[4], bh[4], bl[4];
    const int g = l >> 4;
    const int rl = l & 15;
#pragma unroll
    for (int m = 0; m < 4; ++m) {
      int ra = wr * 64 + m * 16 + rl;
      int idx = ra * 32 + (g ^ ((ra >> 1) & 3)) * 8;
      ah[m] = *(const short8*)&lds[0][idx];
      if constexpr (ATERMS == 3) al_[m] = *(const short8*)&lds[1][idx];
    }
#pragma unroll
    for (int n = 0; n < 4; ++n) {
      int rb = wc * 64 + n * 16 + rl;
      int idx = rb * 32 + (g ^ ((rb >> 1) & 3)) * 8;
      bh[n] = *(const short8*)&lds[NT - 2][idx];
      bl[n] = *(const short8*)&lds[NT - 1][idx];
    }
#pragma unroll
    for (int m = 0; m < 4; ++m)
#pragma unroll
      for (int n = 0; n < 4; ++n) {
        acc[m][n] = __builtin_amdgcn_mfma_f32_16x16x32_bf16(ah[m], bh[n], acc[m][n], 0, 0, 0);
        if constexpr (ATERMS == 3)
          acc[m][n] = __builtin_amdgcn_mfma_f32_16x16x32_bf16(al_[m], bh[n], acc[m][n], 0, 0, 0);
        acc[m][n] = __builtin_amdgcn_mfma_f32_16x16x32_bf16(ah[m], bl[n], acc[m][n], 0, 0, 0);
      }
  }

  // ---- epilogue: C/D layout col = lane&15, row = (lane>>4)*4 + reg ----
  const int cg = l & 15;
#pragma unroll
  for (int m = 0; m < 4; ++m)
#pragma unroll
    for (int n = 0; n < 4; ++n) {
      int col = bn + wc * 64 + n * 16 + cg;
      float bb = bias[col];
#pragma unroll
      for (int r = 0; r < 4; ++r) {
        int row = bm + wr * 64 + m * 16 + (l >> 4) * 4 + r;
        float v = acc[m][n][r] + bb;
        if (RELU) v = fmaxf(v, 0.f);
        size_t o = (size_t)row * N + col;
        if constexpr (EPI == 0) {
          C[o] = v;
        } else if constexpr (EPI == 1) {
          ushortT hh = f2bf(v);
          Chi[o] = hh;
          Clo[o] = f2bf(v - bf2f(hh));
        } else {
          Chi[o] = f2bf(v);
        }
      }
    }
}

// ============================================================================
// Block-sparse flash attention, v5: single-bf16 MFMA + balanced 1D grid.
// wgid = qb*32 + h*4 + b  -> the 32 heavy qb=0 blocks (32 iters vs ~5.5 avg)
// land on 32 DISTINCT CUs and launch FIRST (fixes the round-7 resonance where
// they stacked on ~8 CUs). One block (256 thr, 4 waves) per (qb, h, b); wave w
// owns q rows 16w..16w+15. LDS 36.9 KB -> 4 blocks/CU (launch_bounds(256,4)).
// QK^T: 8 MFMA/wave/iter; softmax in registers (16-lane shfl_xor groups),
// 1/8 scale folded in fp32; P bf16 via wave-private LDS; PV: 8 MFMA.
// ============================================================================
__global__ __launch_bounds__(256, 4) void attn_mfma(const ushortT* __restrict__ qkv,
                                                    ushortT* __restrict__ ctx,
                                                    MaskBits mask) {
  constexpr int LP = 72;                 // LDS pitch in bf16 (144 B, 16B-aligned)
  __shared__ ushortT Qh[64][LP];
  __shared__ ushortT Kh[64][LP];
  __shared__ ushortT Vth[64][LP];        // [d][key]
  __shared__ ushortT Pw[4][16][LP];      // per-wave [q][key]

  const int wgid = blockIdx.x;
  const int qb = wgid >> 5;
  const int hd = (wgid >> 2) & 7;
  const int b = wgid & 3;
  const int tid = threadIdx.x;
  const int w = tid >> 6;
  const int l = tid & 63;
  const int g = l >> 4;                  // k-group 0..3
  const int rl = l & 15;                 // row/col within 16
  const size_t RS = 1536;

  const ushortT* qbase = qkv + ((size_t)b * 2048 + (size_t)qb * 64) * RS + hd * 64;
  const ushortT* kbase = qkv + (size_t)b * 2048 * RS + 512 + hd * 64;
  const ushortT* vbase = qkv + (size_t)b * 2048 * RS + 1024 + hd * 64;

  // staging coords
  const int kr = tid >> 2;               // row 0..63
  const int kc = (tid & 3) * 16;         // col chunk
  const int k0 = (tid & 15) * 4;         // V: 4 keys
  const int dg = (tid >> 4) * 4;         // V: 4 d's

  { // stage Q (row-major)
    const ushortT* ph = qbase + (size_t)kr * RS + kc;
    *(ushort8*)&Qh[kr][kc]     = *(const ushort8*)ph;
    *(ushort8*)&Qh[kr][kc + 8] = *(const ushort8*)(ph + 8);
  }

  float m_[4] = {-INFINITY, -INFINITY, -INFINITY, -INFINITY};
  float l_[4] = {0.f, 0.f, 0.f, 0.f};
  f32x4 acc[4] = {};                     // O strip: [ntile d][4 q-rows]

  u32 rem = mask.row[qb];
  while (rem) {
    const int kb = (int)__builtin_ctz(rem);
    rem &= rem - 1u;

    // ---- global loads (K rows, V 4x4 sub-block) ----
    const ushortT* ph = kbase + (size_t)(kb * 64 + kr) * RS + kc;
    ushort8 kh0 = *(const ushort8*)ph, kh1 = *(const ushort8*)(ph + 8);
    ushortT vbh[4][4];
#pragma unroll
    for (int i = 0; i < 4; ++i) {
      const ushortT* pvh = vbase + (size_t)(kb * 64 + k0 + i) * RS + dg;
      *(ushort4*)vbh[i] = *(const ushort4*)pvh;
    }

    __syncthreads();                     // all waves done reading prev K/Vt

    // ---- LDS writes: K row-major, V transposed ----
    *(ushort8*)&Kh[kr][kc]     = kh0;
    *(ushort8*)&Kh[kr][kc + 8] = kh1;
#pragma unroll
    for (int dd = 0; dd < 4; ++dd) {
      ushort4 oh = {vbh[0][dd], vbh[1][dd], vbh[2][dd], vbh[3][dd]};
      *(ushort4*)&Vth[dg + dd][k0] = oh;
    }
    __syncthreads();

    // ---- QK^T: acc strips of 16 keys, 8 MFMA ----
    short8 qah[2];
#pragma unroll
    for (int ds = 0; ds < 2; ++ds)
      qah[ds] = *(const short8*)&Qh[16 * w + rl][ds * 32 + g * 8];
    f32x4 sc[4] = {};
#pragma unroll
    for (int t = 0; t < 4; ++t) {
#pragma unroll
      for (int ds = 0; ds < 2; ++ds) {
        short8 kbh = *(const short8*)&Kh[16 * t + rl][ds * 32 + g * 8];
        sc[t] = __builtin_amdgcn_mfma_f32_16x16x32_bf16(qah[ds], kbh, sc[t], 0, 0, 0);
      }
    }

    // ---- register online softmax (rows g*4+r, cols t*16+rl) ----
    float al[4];
#pragma unroll
    for (int r = 0; r < 4; ++r) {
      float s0 = sc[0][r] * 0.125f, s1 = sc[1][r] * 0.125f;
      float s2 = sc[2][r] * 0.125f, s3 = sc[3][r] * 0.125f;
      float mx = fmaxf(fmaxf(s0, s1), fmaxf(s2, s3));
      mx = fmaxf(mx, __shfl_xor(mx, 1, 64));
      mx = fmaxf(mx, __shfl_xor(mx, 2, 64));
      mx = fmaxf(mx, __shfl_xor(mx, 4, 64));
      mx = fmaxf(mx, __shfl_xor(mx, 8, 64));
      float mn = fmaxf(m_[r], mx);
      al[r] = __expf(m_[r] - mn);        // 0 on first block
      m_[r] = mn;
      float p0 = __expf(s0 - mn), p1 = __expf(s1 - mn);
      float p2 = __expf(s2 - mn), p3 = __expf(s3 - mn);
      float sum = p0 + p1 + p2 + p3;
      sum += __shfl_xor(sum, 1, 64);
      sum += __shfl_xor(sum, 2, 64);
      sum += __shfl_xor(sum, 4, 64);
      sum += __shfl_xor(sum, 8, 64);
      l_[r] = l_[r] * al[r] + sum;
      // P -> bf16, wave-private LDS strip [q row][key col]
      Pw[w][g * 4 + r][0 * 16 + rl] = f2bf(p0);
      Pw[w][g * 4 + r][1 * 16 + rl] = f2bf(p1);
      Pw[w][g * 4 + r][2 * 16 + rl] = f2bf(p2);
      Pw[w][g * 4 + r][3 * 16 + rl] = f2bf(p3);
    }

    // ---- rescale O ----
#pragma unroll
    for (int nt = 0; nt < 4; ++nt)
#pragma unroll
      for (int r = 0; r < 4; ++r) acc[nt][r] *= al[r];

    // ---- PV: O += P · V  (wave-private P, same-wave ds order), 8 MFMA ----
    short8 pa[2];
#pragma unroll
    for (int ks = 0; ks < 2; ++ks)
      pa[ks] = *(const short8*)&Pw[w][rl][ks * 32 + g * 8];
#pragma unroll
    for (int nt = 0; nt < 4; ++nt) {
#pragma unroll
      for (int ks = 0; ks < 2; ++ks) {
        short8 vh = *(const short8*)&Vth[nt * 16 + rl][ks * 32 + g * 8];
        acc[nt] = __builtin_amdgcn_mfma_f32_16x16x32_bf16(pa[ks], vh, acc[nt], 0, 0, 0);
      }
    }
  }

  // ---- epilogue: divide by l, single bf16 ----
  float inv[4];
#pragma unroll
  for (int r = 0; r < 4; ++r) inv[r] = 1.f / l_[r];
  size_t obase = ((size_t)b * 2048 + (size_t)qb * 64 + 16 * w + g * 4) * 512 + hd * 64 + rl;
#pragma unroll
  for (int nt = 0; nt < 4; ++nt)
#pragma unroll
    for (int r = 0; r < 4; ++r) {
      float v = acc[nt][r] * inv[r];
      size_t o = obase + (size_t)r * 512 + nt * 16;
      ctx[o] = f2bf(v);
    }
}

// ============================================================================
// Fused residual add + LayerNorm over D=512. One block (256 thr) per row.
// SPLIT: additionally emit hi/lo bf16 copies of the output.
// ============================================================================
template<bool SPLIT>
__global__ __launch_bounds__(256) void add_ln(const float* __restrict__ a,
                                              const float* __restrict__ bsrc,
                                              const float* __restrict__ g,
                                              const float* __restrict__ beta,
                                              float* __restrict__ out,
                                              ushortT* __restrict__ ohi,
                                              ushortT* __restrict__ olo) {
  const int row = blockIdx.x;
  const int tid = threadIdx.x;
  const float2* a2 = (const float2*)(a + (size_t)row * 512);
  const float2* b2 = (const float2*)(bsrc + (size_t)row * 512);
  float2 va = a2[tid], vb = b2[tid];
  float x0 = va.x + vb.x, x1 = va.y + vb.y;
  float s = x0 + x1;
  float q = x0 * x0 + x1 * x1;
#pragma unroll
  for (int off = 32; off >= 1; off >>= 1) {
    s += __shfl_xor(s, off, 64);
    q += __shfl_xor(q, off, 64);
  }
  __shared__ float ws[4], wq[4];
  int wid = tid >> 6, lane = tid & 63;
  if (lane == 0) { ws[wid] = s; wq[wid] = q; }
  __syncthreads();
  float ts = ws[0] + ws[1] + ws[2] + ws[3];
  float tq = wq[0] + wq[1] + wq[2] + wq[3];
  float mu = ts * (1.0f / 512.0f);
  float var = tq * (1.0f / 512.0f) - mu * mu;
  float rstd = rsqrtf(var + 1e-5f);
  const float2* g2 = (const float2*)g;
  const float2* be2 = (const float2*)beta;
  float2 vg = g2[tid], vbt = be2[tid];
  float2 r;
  r.x = (x0 - mu) * rstd * vg.x + vbt.x;
  r.y = (x1 - mu) * rstd * vg.y + vbt.y;
  size_t o = (size_t)row * 512 + tid * 2;
  *(float2*)(out + o) = r;
  if (SPLIT) {
    ushort2 h, l;
    h.x = f2bf(r.x); l.x = f2bf(r.x - bf2f(h.x));
    h.y = f2bf(r.y); l.y = f2bf(r.y - bf2f(h.y));
    *(ushort2*)(ohi + o) = h;
    *(ushort2*)(olo + o) = l;
  }
}

// ============================================================================
// Launch. Workspace (bytes, total 146.8 MB; 184.5 MB proven-safe in round 1):
//   A [0, 12.58M)          weight splits (persistent)
//   B [12.58M, 29.36M)     xs_h / xs_l
//   C [29.36M, 54.53M)     qkv (single bf16)
//   D [54.53M, 62.91M)     ctx (single bf16)
//   E [62.91M, 79.69M)     sa fp32 -> later ff fp32
//   F [79.69M, 96.47M)     x1 fp32
//   G [96.47M, 113.25M)    x1_h / x1_l
//   H [113.25M, 146.80M)   mid (single bf16)
// ============================================================================
extern "C" void kernel_launch(void* const* d_in, const int* in_sizes, int n_in,
                              void* d_out, int out_size, void* d_ws, size_t ws_size,
                              hipStream_t stream) {
  const float* x     = (const float*)d_in[0];
  const float* w_in  = (const float*)d_in[1];
  const float* b_in  = (const float*)d_in[2];
  const float* w_out = (const float*)d_in[3];
  const float* b_out = (const float*)d_in[4];
  const float* w1    = (const float*)d_in[5];
  const float* b1    = (const float*)d_in[6];
  const float* w2    = (const float*)d_in[7];
  const float* b2    = (const float*)d_in[8];
  const float* g1    = (const float*)d_in[9];
  const float* be1   = (const float*)d_in[10];
  const float* g2    = (const float*)d_in[11];
  const float* be2   = (const float*)d_in[12];
  float* out = (float*)d_out;

  char* W = (char*)d_ws;
  // A: weight splits
  ushortT* wi_h = (ushortT*)(W + 0);             // 1536x512
  ushortT* wi_l = (ushortT*)(W + 1572864);
  ushortT* wo_h = (ushortT*)(W + 3145728);       // 512x512
  ushortT* wo_l = (ushortT*)(W + 3670016);
  ushortT* w1_h = (ushortT*)(W + 4194304);       // 2048x512
  ushortT* w1_l = (ushortT*)(W + 6291456);
  ushortT* w2_h = (ushortT*)(W + 8388608);       // 512x2048
  ushortT* w2_l = (ushortT*)(W + 10485760);
  // B: x splits
  ushortT* xs_h = (ushortT*)(W + 12582912);
  ushortT* xs_l = (ushortT*)(W + 20971520);
  // C: qkv single bf16
  ushortT* qkv_b = (ushortT*)(W + 29360128);     // 8192x1536
  // D: ctx single bf16
  ushortT* ctx_b = (ushortT*)(W + 54525952);     // 8192x512
  // E: sa fp32 -> ff fp32
  float*   sa    = (float*)(W + 62914560);
  float*   ff    = (float*)(W + 62914560);
  // F: x1 fp32
  float*   x1    = (float*)(W + 79691776);
  // G: x1 splits
  ushortT* x1_h  = (ushortT*)(W + 96468992);
  ushortT* x1_l  = (ushortT*)(W + 104857600);
  // H: mid single bf16
  ushortT* mid   = (ushortT*)(W + 113246208);    // 8192x2048

  dim3 blk(256);

  // 0. splits: x and all weights
  split_bf16<<<dim3(2048), blk, 0, stream>>>(x, xs_h, xs_l, 8192 * 512 / 4);
  split_bf16<<<dim3(768), blk, 0, stream>>>(w_in, wi_h, wi_l, 1536 * 512 / 4);
  split_bf16<<<dim3(256), blk, 0, stream>>>(w_out, wo_h, wo_l, 512 * 512 / 4);
  split_bf16<<<dim3(1024), blk, 0, stream>>>(w1, w1_h, w1_l, 2048 * 512 / 4);
  split_bf16<<<dim3(1024), blk, 0, stream>>>(w2, w2_h, w2_l, 512 * 2048 / 4);

  // 1. qkv = x @ in_proj_w^T + b      [8192,1536] -> single bf16
  gemm_split<3, 2, false><<<dim3(1536 / 128, 8192 / 128), blk, 0, stream>>>(
      xs_h, xs_l, wi_h, wi_l, b_in, nullptr, qkv_b, nullptr, 1536, 512);
  // 2. MFMA block-sparse attention -> ctx (single bf16); balanced 1D grid
  attn_mfma<<<dim3(1024), blk, 0, stream>>>(qkv_b, ctx_b, kMask);
  // 3. sa = ctx @ out_proj_w^T + b    [8192,512] fp32 (2-term)
  gemm_split<2, 0, false><<<dim3(512 / 128, 8192 / 128), blk, 0, stream>>>(
      ctx_b, nullptr, wo_h, wo_l, b_out, sa, nullptr, nullptr, 512, 512);
  // 4. x1 = LN(x + sa)  (+ split)
  add_ln<true><<<dim3(8192), blk, 0, stream>>>(x, sa, g1, be1, x1, x1_h, x1_l);
  // 5. mid = relu(x1 @ w1^T + b1)     [8192,2048] single bf16
  gemm_split<3, 2, true><<<dim3(2048 / 128, 8192 / 128), blk, 0, stream>>>(
      x1_h, x1_l, w1_h, w1_l, b1, nullptr, mid, nullptr, 2048, 512);
  // 6. ff = mid @ w2^T + b2           [8192,512] fp32 (2-term)
  gemm_split<2, 0, false><<<dim3(512 / 128, 8192 / 128), blk, 0, stream>>>(
      mid, nullptr, w2_h, w2_l, b2, ff, nullptr, nullptr, 512, 2048);
  // 7. out = LN(x1 + ff)
  add_ln<false><<<dim3(8192), blk, 0, stream>>>(x1, ff, g2, be2, out, nullptr, nullptr);
}